// Round 1
// baseline (1703.449 us; speedup 1.0000x reference)
//
#include <hip/hip_runtime.h>
#include <hip/hip_bf16.h>
#include <stdint.h>

// Problem constants (fixed by setup_inputs)
#define NN 16384
#define DD 512
#define BM 128
#define BN 128
#define BK 64
#define NCT 128       // column tiles (= NN/BN) = per-row partial segments
#define NEG_INF (-3.0e38f)

// R9: eliminate the second GEMM. Pass 1 stores sim as fp16 (536 MB) while
// computing top-k partials; pass 2 becomes a memory-bound streaming scan
// (count + max) at ~85-110 µs instead of recomputing 2.75e11 FLOP (~750 µs).
// Runtime ws_size gate: falls back to the verified 2-GEMM path if the
// workspace can't hold the sim matrix.

typedef unsigned short u16;
typedef _Float16 f16;
typedef __attribute__((ext_vector_type(8))) __bf16 bf16x8;   // MFMA A/B operand
typedef __attribute__((ext_vector_type(8))) short sh8;       // 16B vector
typedef __attribute__((ext_vector_type(8))) _Float16 f16x8;  // 16B of fp16
typedef __attribute__((ext_vector_type(4))) float f32x4;     // MFMA C/D

__device__ __forceinline__ u16 f2bf(float f) {  // RNE fp32->bf16
  uint32_t x = __float_as_uint(f);
  x += 0x7fffu + ((x >> 16) & 1u);
  return (u16)(x >> 16);
}
__device__ __forceinline__ float bf2f(u16 u) {
  return __uint_as_float(((uint32_t)u) << 16);
}

// async global->LDS, 16B per lane; lds base wave-uniform.
__device__ __forceinline__ void gload_lds16(const u16* g, u16* lds) {
  __builtin_amdgcn_global_load_lds(
      (const __attribute__((address_space(1))) uint32_t*)g,
      (__attribute__((address_space(3))) uint32_t*)lds,
      16, 0, 0);
}

// Insert v into descending-sorted 10-element register array.
__device__ __forceinline__ void ins10(float t[10], float v) {
  #pragma unroll
  for (int j = 0; j < 10; ++j) {
    float hi = fmaxf(t[j], v);
    v = fminf(t[j], v);
    t[j] = hi;
  }
}

__global__ __launch_bounds__(256) void cast_kernel(const float* __restrict__ src,
                                                   u16* __restrict__ dst) {
  int i = (blockIdx.x * 256 + threadIdx.x) * 8;
  const float4* s4 = reinterpret_cast<const float4*>(src + i);
  float4 a = s4[0], b = s4[1];
  sh8 o;
  o[0] = (short)f2bf(a.x); o[1] = (short)f2bf(a.y);
  o[2] = (short)f2bf(a.z); o[3] = (short)f2bf(a.w);
  o[4] = (short)f2bf(b.x); o[5] = (short)f2bf(b.y);
  o[6] = (short)f2bf(b.z); o[7] = (short)f2bf(b.w);
  *reinterpret_cast<sh8*>(dst + i) = o;
}

// diag[r] = <Lb_r, Rb_r> — one wave per row
__global__ __launch_bounds__(256) void diag_kernel(const u16* __restrict__ Lb,
                                                   const u16* __restrict__ Rb,
                                                   float* __restrict__ diag) {
  int r = blockIdx.x * 4 + (threadIdx.x >> 6);
  int lane = threadIdx.x & 63;
  sh8 a = *reinterpret_cast<const sh8*>(Lb + (size_t)r * DD + lane * 8);
  sh8 b = *reinterpret_cast<const sh8*>(Rb + (size_t)r * DD + lane * 8);
  float s = 0.f;
  #pragma unroll
  for (int j = 0; j < 8; ++j) s += bf2f((u16)a[j]) * bf2f((u16)b[j]);
  #pragma unroll
  for (int off = 32; off > 0; off >>= 1) s += __shfl_down(s, off);
  if (lane == 0) diag[r] = s;
}

// Shared block-coordinate decode + K-loop body (single 128x128 tile, K=512).
// xcd = blk&7 -> fixed 16-rowtile A-band per XCD; coltile sweeps slowly.
#define DECODE_TILE()                                   \
  const int xcd = blockIdx.x & 7;                       \
  const int idx = blockIdx.x >> 3;                      \
  const int rowtile = xcd * 16 + (idx & 15);            \
  const int coltile = idx >> 4;                         \
  const int rowbase = rowtile * BM;                     \
  const int colbase = coltile * BN;                     \
  const int tid = threadIdx.x;                          \
  const int w = tid >> 6;                               \
  const int lane = tid & 63;                            \
  const int quad = lane >> 4;                           \
  const int l16 = lane & 15;                            \
  const int wr = (w >> 1) * 64;                         \
  const int wc = (w & 1) * 64;                          \
  const int lrow8 = lane >> 3;                          \
  const int gran = lane & 7;

#define GEMM_K_LOOP(sA, sB)                                                     \
  f32x4 acc[4][4];                                                              \
  _Pragma("unroll")                                                             \
  for (int a_ = 0; a_ < 4; ++a_)                                                \
    _Pragma("unroll")                                                           \
    for (int b_ = 0; b_ < 4; ++b_) acc[a_][b_] = (f32x4){0.f, 0.f, 0.f, 0.f};   \
  {                                                                             \
    const u16* gA = A + (size_t)(rowbase + w * 32 + lrow8) * DD + gran * 8;     \
    const u16* gB = B + (size_t)(colbase + w * 32 + lrow8) * DD + gran * 8;     \
    for (int kk = 0; kk < DD; kk += BK) {                                       \
      _Pragma("unroll")                                                         \
      for (int it = 0; it < 4; ++it) {                                          \
        gload_lds16(gA + (size_t)it * 8 * DD + kk, sA + (w * 32 + it * 8) * 64);\
        gload_lds16(gB + (size_t)it * 8 * DD + kk, sB + (w * 32 + it * 8) * 64);\
      }                                                                         \
      __syncthreads();                                                          \
      _Pragma("unroll")                                                         \
      for (int ks = 0; ks < BK; ks += 32) {                                     \
        bf16x8 af[4], bfr[4];                                                   \
        _Pragma("unroll")                                                       \
        for (int f = 0; f < 4; ++f) {                                           \
          af[f]  = *reinterpret_cast<const bf16x8*>(sA + (wr + 16 * f + l16) * 64 + ks + quad * 8); \
          bfr[f] = *reinterpret_cast<const bf16x8*>(sB + (wc + 16 * f + l16) * 64 + ks + quad * 8); \
        }                                                                       \
        _Pragma("unroll")                                                       \
        for (int fr = 0; fr < 4; ++fr)                                          \
          _Pragma("unroll")                                                     \
          for (int fc = 0; fc < 4; ++fc)                                        \
            acc[fr][fc] = __builtin_amdgcn_mfma_f32_16x16x32_bf16(af[fr], bfr[fc], acc[fr][fc], 0, 0, 0); \
      }                                                                         \
      __syncthreads();                                                          \
    }                                                                           \
  }

// Pass 1: G2 tile + row top-10 partials (RL) + col top-10 partials (LR).
// rowp[row][coltile][10] f16 ; colp[col][rowtile][10] f16 (sorted desc).
// If sim != nullptr, also dump the fp16 tile to global so pass 2 becomes a
// streaming scan instead of a second GEMM.
__global__ __launch_bounds__(256) void gemm_topk(const u16* __restrict__ A,
                                                 const u16* __restrict__ B,
                                                 f16* __restrict__ rowp,
                                                 f16* __restrict__ colp,
                                                 f16* __restrict__ sim) {
  __shared__ __align__(16) u16 smem[17408];  // 34816 B (epi fp16 view 128x136)
  u16* sA = smem;
  u16* sB = smem + 8192;
  DECODE_TILE()
  GEMM_K_LOOP(sA, sB)

  // fp16 dump [128][136]
  f16* hC = reinterpret_cast<f16*>(smem);
  #pragma unroll
  for (int fr = 0; fr < 4; ++fr)
    #pragma unroll
    for (int fc = 0; fc < 4; ++fc)
      #pragma unroll
      for (int reg = 0; reg < 4; ++reg)
        hC[(wr + 16 * fr + quad * 4 + reg) * 136 + wc + 16 * fc + l16] =
            (f16)acc[fr][fc][reg];
  __syncthreads();
  // global sim store: 8 iters x 256 threads x 8 f16 (16B each; 16 consecutive
  // lanes cover one 256B row segment -> coalesced)
  if (sim != nullptr) {
    f16* gs = sim + (size_t)rowbase * NN + colbase;
    #pragma unroll
    for (int itw = 0; itw < 8; ++itw) {
      int idx = itw * 2048 + tid * 8;
      int rr = idx >> 7, cc = idx & 127;
      f16x8 v = *reinterpret_cast<const f16x8*>(hC + rr * 136 + cc);
      *reinterpret_cast<f16x8*>(gs + (size_t)rr * NN + cc) = v;
    }
  }
  // row scan: thread owns (row = tid>>1, col-half = tid&1)
  float tk[10];
  #pragma unroll
  for (int j = 0; j < 10; ++j) tk[j] = NEG_INF;
  {
    const f16* q = hC + (tid >> 1) * 136 + (tid & 1) * 64;
    #pragma unroll
    for (int c8 = 0; c8 < 8; ++c8) {
      f16x8 v8 = *reinterpret_cast<const f16x8*>(q + c8 * 8);
      #pragma unroll
      for (int j = 0; j < 8; ++j) {
        float v = (float)v8[j];
        if (v > tk[9]) ins10(tk, v);
      }
    }
  }
  // col scan: thread owns (col = tid&127, row-half = tid>>7)
  float ck[10];
  #pragma unroll
  for (int j = 0; j < 10; ++j) ck[j] = NEG_INF;
  {
    const int c = tid & 127, rh = tid >> 7;
    #pragma unroll 8
    for (int i = 0; i < 64; ++i) {
      float v = (float)hC[(rh * 64 + i) * 136 + c];
      if (v > ck[9]) ins10(ck, v);
    }
  }
  __syncthreads();
  // merge col halves -> colp
  float* sP = reinterpret_cast<float*>(smem);  // [128][21]
  {
    const int c = tid & 127, rh = tid >> 7;
    #pragma unroll
    for (int j = 0; j < 10; ++j) sP[c * 21 + rh * 10 + j] = ck[j];
  }
  __syncthreads();
  if (tid < 128) {
    float best[10];
    #pragma unroll
    for (int j = 0; j < 10; ++j) best[j] = NEG_INF;
    #pragma unroll
    for (int j = 0; j < 20; ++j) {
      float v = sP[tid * 21 + j];
      if (v > best[9]) ins10(best, v);
    }
    f16* o = colp + ((size_t)(colbase + tid) * NCT + rowtile) * 10;
    #pragma unroll
    for (int j = 0; j < 10; ++j) o[j] = (f16)best[j];
  }
  __syncthreads();
  // merge row halves -> rowp
  float* sM = reinterpret_cast<float*>(smem);  // [128][21]
  #pragma unroll
  for (int j = 0; j < 10; ++j)
    sM[(tid >> 1) * 21 + (tid & 1) * 10 + j] = tk[j];
  __syncthreads();
  if (tid < 128) {
    float best[10];
    #pragma unroll
    for (int j = 0; j < 10; ++j) best[j] = NEG_INF;
    #pragma unroll
    for (int j = 0; j < 20; ++j) {
      float v = sM[tid * 21 + j];
      if (v > best[9]) ins10(best, v);
    }
    f16* o = rowp + ((size_t)(rowbase + tid) * NCT + coltile) * 10;
    #pragma unroll
    for (int j = 0; j < 10; ++j) o[j] = (f16)best[j];
  }
}

// Pass 2 (fallback path): G2 tile + count(2v - p[col] > thr[row]) and max.
__global__ __launch_bounds__(256) void gemm_rank(const u16* __restrict__ A,
                                                 const u16* __restrict__ B,
                                                 const float* __restrict__ p,
                                                 const float* __restrict__ thr,
                                                 int* __restrict__ cnt_out,
                                                 float* __restrict__ mx_out) {
  __shared__ __align__(16) u16 smem[16384];  // 32768 B
  u16* sA = smem;
  u16* sB = smem + 8192;
  DECODE_TILE()

  float thrv[16];
  #pragma unroll
  for (int i = 0; i < 16; ++i)
    thrv[i] = thr[rowbase + wr + 16 * (i >> 2) + quad * 4 + (i & 3)];
  float pv[4];
  #pragma unroll
  for (int fc = 0; fc < 4; ++fc) pv[fc] = p[colbase + wc + 16 * fc + l16];

  GEMM_K_LOOP(sA, sB)

  int cnt[16];
  float mx[16];
  #pragma unroll
  for (int i = 0; i < 16; ++i) { cnt[i] = 0; mx[i] = NEG_INF; }
  #pragma unroll
  for (int fc = 0; fc < 4; ++fc)
    #pragma unroll
    for (int fr = 0; fr < 4; ++fr)
      #pragma unroll
      for (int reg = 0; reg < 4; ++reg) {
        float t2 = 2.f * acc[fr][fc][reg] - pv[fc];
        int idx = fr * 4 + reg;
        cnt[idx] += (t2 > thrv[idx]) ? 1 : 0;
        mx[idx] = fmaxf(mx[idx], t2);
      }

  // reduce across 16 col-lanes, then combine the two col-half waves per row
  float* sMx = reinterpret_cast<float*>(smem);        // [4][64]
  int*   sCn = reinterpret_cast<int*>(smem) + 256;    // [4][64]
  #pragma unroll
  for (int idx = 0; idx < 16; ++idx) {
    int c = cnt[idx];
    float m = mx[idx];
    #pragma unroll
    for (int off = 1; off < 16; off <<= 1) {
      c += __shfl_xor(c, off);
      m = fmaxf(m, __shfl_xor(m, off));
    }
    if (l16 == 0) {
      int rloc = 16 * (idx >> 2) + quad * 4 + (idx & 3);
      sMx[w * 64 + rloc] = m;
      sCn[w * 64 + rloc] = c;
    }
  }
  __syncthreads();
  if (tid < 128) {
    int half = tid >> 6, rloc = tid & 63;
    int c = sCn[(half * 2) * 64 + rloc] + sCn[(half * 2 + 1) * 64 + rloc];
    float m = fmaxf(sMx[(half * 2) * 64 + rloc], sMx[(half * 2 + 1) * 64 + rloc]);
    cnt_out[(size_t)(rowbase + tid) * NCT + coltile] = c;
    mx_out[(size_t)(rowbase + tid) * NCT + coltile] = m;
  }
}

// Pass 2 (store path): streaming scan of fp16 sim. 4 rows per block,
// 256 threads cover the 16384 columns in 8 strided f16x8 steps.
// Writes rank count and max directly to d_out. Memory-bound: 536 MB HBM.
__global__ __launch_bounds__(256) void scan_kernel(const f16* __restrict__ sim,
                                                   const float* __restrict__ p,
                                                   const float* __restrict__ thr,
                                                   float* __restrict__ out) {
  const int tid = threadIdx.x;
  const int row0 = blockIdx.x * 4;
  float t[4];
  #pragma unroll
  for (int r = 0; r < 4; ++r) t[r] = thr[row0 + r];
  int cnt[4] = {0, 0, 0, 0};
  float m[4] = {NEG_INF, NEG_INF, NEG_INF, NEG_INF};
  for (int it = 0; it < 8; ++it) {
    int c0 = it * 2048 + tid * 8;
    float pv[8];
    {
      const float4* p4 = reinterpret_cast<const float4*>(p + c0);
      float4 a = p4[0], b = p4[1];
      pv[0] = a.x; pv[1] = a.y; pv[2] = a.z; pv[3] = a.w;
      pv[4] = b.x; pv[5] = b.y; pv[6] = b.z; pv[7] = b.w;
    }
    #pragma unroll
    for (int r = 0; r < 4; ++r) {
      f16x8 v8 = *reinterpret_cast<const f16x8*>(sim + (size_t)(row0 + r) * NN + c0);
      #pragma unroll
      for (int j = 0; j < 8; ++j) {
        float t2 = 2.f * (float)v8[j] - pv[j];
        cnt[r] += (t2 > t[r]) ? 1 : 0;
        m[r] = fmaxf(m[r], t2);
      }
    }
  }
  // reduce: wave shuffle (64 lanes) then 4 waves via LDS
  __shared__ float sM[4][4];
  __shared__ int sC[4][4];
  const int lane = tid & 63, w = tid >> 6;
  #pragma unroll
  for (int r = 0; r < 4; ++r) {
    int c = cnt[r];
    float mm = m[r];
    #pragma unroll
    for (int off = 32; off > 0; off >>= 1) {
      c += __shfl_down(c, off);
      mm = fmaxf(mm, __shfl_down(mm, off));
    }
    if (lane == 0) { sC[r][w] = c; sM[r][w] = mm; }
  }
  __syncthreads();
  if (tid < 4) {
    int c = sC[tid][0] + sC[tid][1] + sC[tid][2] + sC[tid][3];
    float mm = fmaxf(fmaxf(sM[tid][0], sM[tid][1]), fmaxf(sM[tid][2], sM[tid][3]));
    out[row0 + tid] = (float)c;          // rank (count strictly greater)
    out[NN + row0 + tid] = mm;           // top-1 csls value
  }
}

// p[l] = mean(top10 of rowp[l][*]) + mean(top10 of colp[l][*]); thr = 2*diag - p
__global__ __launch_bounds__(256) void p_kernel(const f16* __restrict__ rowp,
                                                const f16* __restrict__ colp,
                                                const float* __restrict__ diag,
                                                float* __restrict__ pout,
                                                float* __restrict__ throut) {
  int l = blockIdx.x * 256 + threadIdx.x;
  float b1[10], b2[10];
  #pragma unroll
  for (int j = 0; j < 10; ++j) { b1[j] = NEG_INF; b2[j] = NEG_INF; }
  for (int s = 0; s < NCT; ++s) {
    const f16* q1 = rowp + ((size_t)l * NCT + s) * 10;
    for (int j = 0; j < 10; ++j) {   // sorted desc -> early break
      float v = (float)q1[j];
      if (v > b1[9]) ins10(b1, v); else break;
    }
    const f16* q2 = colp + ((size_t)l * NCT + s) * 10;
    for (int j = 0; j < 10; ++j) {
      float v = (float)q2[j];
      if (v > b2[9]) ins10(b2, v); else break;
    }
  }
  float s1 = 0.f, s2 = 0.f;
  #pragma unroll
  for (int j = 0; j < 10; ++j) { s1 += b1[j]; s2 += b2[j]; }
  float pv = (s1 + s2) * 0.1f;
  pout[l] = pv;
  throut[l] = 2.f * diag[l] - pv;
}

__global__ __launch_bounds__(256) void final_kernel(const int* __restrict__ cnt,
                                                    const float* __restrict__ mx,
                                                    float* __restrict__ out) {
  int r = blockIdx.x * 256 + threadIdx.x;
  int c = 0;
  float m = NEG_INF;
  for (int s = 0; s < NCT; ++s) {
    c += cnt[(size_t)r * NCT + s];
    m = fmaxf(m, mx[(size_t)r * NCT + s]);
  }
  out[r] = (float)c;   // rank of the diagonal element (count strictly greater)
  out[NN + r] = m;     // top-1 csls value
}

extern "C" void kernel_launch(void* const* d_in, const int* in_sizes, int n_in,
                              void* d_out, int out_size, void* d_ws, size_t ws_size,
                              hipStream_t stream) {
  const float* L = (const float*)d_in[0];
  const float* R = (const float*)d_in[1];
  char* ws = (char*)d_ws;

  const size_t PARTB = (size_t)NN * NCT * 10 * 2;       // 41.94 MB per partial
  const size_t SIMB  = (size_t)NN * NN * 2;             // 536.87 MB fp16 sim
  const size_t NEED_STORE = (32ull << 20) + SIMB + 2 * PARTB + 3ull * (size_t)NN * 4;

  u16* Lb = (u16*)ws;                                   // 16 MB
  u16* Rb = (u16*)(ws + (16ull << 20));                 // 16 MB

  // 1) fp32 -> bf16 casts
  cast_kernel<<<(NN * DD / (256 * 8)), 256, 0, stream>>>(L, Lb);
  cast_kernel<<<(NN * DD / (256 * 8)), 256, 0, stream>>>(R, Rb);

  if (ws_size >= NEED_STORE) {
    // ---- store path: one GEMM, pass 2 is a streaming scan ----
    f16*   sim    = (f16*)(ws + (32ull << 20));
    f16*   rowp   = (f16*)(ws + (32ull << 20) + SIMB);
    f16*   colp   = (f16*)(ws + (32ull << 20) + SIMB + PARTB);
    char*  tail   = ws + (32ull << 20) + SIMB + 2 * PARTB;
    float* diag   = (float*)tail;
    float* pbuf   = (float*)(tail + (size_t)NN * 4);
    float* thrbuf = (float*)(tail + (size_t)NN * 8);

    diag_kernel<<<NN / 4, 256, 0, stream>>>(Lb, Rb, diag);
    gemm_topk<<<(NN / BM) * (NN / BN), 256, 0, stream>>>(Rb, Lb, rowp, colp, sim);
    p_kernel<<<NN / 256, 256, 0, stream>>>(rowp, colp, diag, pbuf, thrbuf);
    scan_kernel<<<NN / 4, 256, 0, stream>>>(sim, pbuf, thrbuf, (float*)d_out);
  } else {
    // ---- fallback: verified 2-GEMM path ----
    f16* rowp = (f16*)(ws + (32ull << 20));
    f16* colp = (f16*)(ws + (32ull << 20) + PARTB);
    size_t off = (32ull << 20) + 2 * PARTB;
    float* diag   = (float*)(ws + off); off += (size_t)NN * 4;
    float* pbuf   = (float*)(ws + off); off += (size_t)NN * 4;
    float* thrbuf = (float*)(ws + off); off += (size_t)NN * 4;
    int*   cntp = (int*)colp;                             // 8.4 MB (colp consumed)
    float* mxp  = (float*)((char*)colp + (20ull << 20));  // 8.4 MB

    diag_kernel<<<NN / 4, 256, 0, stream>>>(Lb, Rb, diag);
    gemm_topk<<<(NN / BM) * (NN / BN), 256, 0, stream>>>(Rb, Lb, rowp, colp, nullptr);
    p_kernel<<<NN / 256, 256, 0, stream>>>(rowp, colp, diag, pbuf, thrbuf);
    gemm_rank<<<(NN / BM) * (NN / BN), 256, 0, stream>>>(Rb, Lb, pbuf, thrbuf, cntp, mxp);
    final_kernel<<<NN / 256, 256, 0, stream>>>(cntp, mxp, (float*)d_out);
  }
}

// Round 2
// 1376.132 us; speedup vs baseline: 1.2379x; 1.2379x over previous
//
#include <hip/hip_runtime.h>
#include <hip/hip_bf16.h>
#include <stdint.h>

// Problem constants (fixed by setup_inputs)
#define NN 16384
#define DD 512
#define BM 128
#define BN 128
#define BK 64
#define NCT 128       // column tiles (= NN/BN) = per-row partial segments
#define NEG_INF (-3.0e38f)

// R10: (a) ADAPTIVE hybrid sim store — store fp16 sim for SC column-tiles
// (whatever the workspace holds), gemm_rank only covers the rest, a
// memory-bound scan covers the stored part. R9's all-or-nothing gate fell
// back (ws < 654 MB) — counters showed fallback timing + no sim writes.
// (b) Packed-f16 top-k epilogue (v_pk_max/min_f16): epilogue was ~350 µs of
// divergent ins10 (VALUBusy 65%, MfmaUtil 11.5%); packed chain processes 2
// candidates per 20-op network, unguarded -> ~2.3x less epilogue VALU.

typedef unsigned short u16;
typedef _Float16 f16;
typedef __attribute__((ext_vector_type(8))) __bf16 bf16x8;   // MFMA A/B operand
typedef __attribute__((ext_vector_type(8))) short sh8;       // 16B vector
typedef __attribute__((ext_vector_type(8))) _Float16 f16x8;  // 16B of fp16
typedef __attribute__((ext_vector_type(4))) float f32x4;     // MFMA C/D

__device__ __forceinline__ u16 f2bf(float f) {  // RNE fp32->bf16
  uint32_t x = __float_as_uint(f);
  x += 0x7fffu + ((x >> 16) & 1u);
  return (u16)(x >> 16);
}
__device__ __forceinline__ float bf2f(u16 u) {
  return __uint_as_float(((uint32_t)u) << 16);
}
__device__ __forceinline__ float f16bits(uint32_t bits) {  // low 16b as f16
  f16 h;
  u16 b = (u16)bits;
  __builtin_memcpy(&h, &b, 2);
  return (float)h;
}
__device__ __forceinline__ uint32_t pk_max16(uint32_t a, uint32_t b) {
  uint32_t d;
  asm("v_pk_max_f16 %0, %1, %2" : "=v"(d) : "v"(a), "v"(b));
  return d;
}
__device__ __forceinline__ uint32_t pk_min16(uint32_t a, uint32_t b) {
  uint32_t d;
  asm("v_pk_min_f16 %0, %1, %2" : "=v"(d) : "v"(a), "v"(b));
  return d;
}

// async global->LDS, 16B per lane; lds base wave-uniform.
__device__ __forceinline__ void gload_lds16(const u16* g, u16* lds) {
  __builtin_amdgcn_global_load_lds(
      (const __attribute__((address_space(1))) uint32_t*)g,
      (__attribute__((address_space(3))) uint32_t*)lds,
      16, 0, 0);
}

// Insert v into descending-sorted 10-element register array (fp32).
__device__ __forceinline__ void ins10(float t[10], float v) {
  #pragma unroll
  for (int j = 0; j < 10; ++j) {
    float hi = fmaxf(t[j], v);
    v = fminf(t[j], v);
    t[j] = hi;
  }
}
// Packed variant: two independent sorted-desc f16 lists in lo/hi halves.
__device__ __forceinline__ void pins10(uint32_t t[10], uint32_t v) {
  #pragma unroll
  for (int j = 0; j < 10; ++j) {
    uint32_t hi = pk_max16(t[j], v);
    v = pk_min16(t[j], v);
    t[j] = hi;
  }
}

__global__ __launch_bounds__(256) void cast_kernel(const float* __restrict__ src,
                                                   u16* __restrict__ dst) {
  int i = (blockIdx.x * 256 + threadIdx.x) * 8;
  const float4* s4 = reinterpret_cast<const float4*>(src + i);
  float4 a = s4[0], b = s4[1];
  sh8 o;
  o[0] = (short)f2bf(a.x); o[1] = (short)f2bf(a.y);
  o[2] = (short)f2bf(a.z); o[3] = (short)f2bf(a.w);
  o[4] = (short)f2bf(b.x); o[5] = (short)f2bf(b.y);
  o[6] = (short)f2bf(b.z); o[7] = (short)f2bf(b.w);
  *reinterpret_cast<sh8*>(dst + i) = o;
}

// diag[r] = <Lb_r, Rb_r> — one wave per row
__global__ __launch_bounds__(256) void diag_kernel(const u16* __restrict__ Lb,
                                                   const u16* __restrict__ Rb,
                                                   float* __restrict__ diag) {
  int r = blockIdx.x * 4 + (threadIdx.x >> 6);
  int lane = threadIdx.x & 63;
  sh8 a = *reinterpret_cast<const sh8*>(Lb + (size_t)r * DD + lane * 8);
  sh8 b = *reinterpret_cast<const sh8*>(Rb + (size_t)r * DD + lane * 8);
  float s = 0.f;
  #pragma unroll
  for (int j = 0; j < 8; ++j) s += bf2f((u16)a[j]) * bf2f((u16)b[j]);
  #pragma unroll
  for (int off = 32; off > 0; off >>= 1) s += __shfl_down(s, off);
  if (lane == 0) diag[r] = s;
}

// Shared block-coordinate decode. xcd = blk&7 -> fixed 16-rowtile A-band per
// XCD; coltile sweeps slowly. ct0 = coltile offset (hybrid gemm_rank).
#define DECODE_TILE(ct0)                                \
  const int xcd = blockIdx.x & 7;                       \
  const int idx = blockIdx.x >> 3;                      \
  const int rowtile = xcd * 16 + (idx & 15);            \
  const int coltile = (ct0) + (idx >> 4);               \
  const int rowbase = rowtile * BM;                     \
  const int colbase = coltile * BN;                     \
  const int tid = threadIdx.x;                          \
  const int w = tid >> 6;                               \
  const int lane = tid & 63;                            \
  const int quad = lane >> 4;                           \
  const int l16 = lane & 15;                            \
  const int wr = (w >> 1) * 64;                         \
  const int wc = (w & 1) * 64;                          \
  const int lrow8 = lane >> 3;                          \
  const int gran = lane & 7;

#define GEMM_K_LOOP(sA, sB)                                                     \
  f32x4 acc[4][4];                                                              \
  _Pragma("unroll")                                                             \
  for (int a_ = 0; a_ < 4; ++a_)                                                \
    _Pragma("unroll")                                                           \
    for (int b_ = 0; b_ < 4; ++b_) acc[a_][b_] = (f32x4){0.f, 0.f, 0.f, 0.f};   \
  {                                                                             \
    const u16* gA = A + (size_t)(rowbase + w * 32 + lrow8) * DD + gran * 8;     \
    const u16* gB = B + (size_t)(colbase + w * 32 + lrow8) * DD + gran * 8;     \
    for (int kk = 0; kk < DD; kk += BK) {                                       \
      _Pragma("unroll")                                                         \
      for (int it = 0; it < 4; ++it) {                                          \
        gload_lds16(gA + (size_t)it * 8 * DD + kk, sA + (w * 32 + it * 8) * 64);\
        gload_lds16(gB + (size_t)it * 8 * DD + kk, sB + (w * 32 + it * 8) * 64);\
      }                                                                         \
      __syncthreads();                                                          \
      _Pragma("unroll")                                                         \
      for (int ks = 0; ks < BK; ks += 32) {                                     \
        bf16x8 af[4], bfr[4];                                                   \
        _Pragma("unroll")                                                       \
        for (int f = 0; f < 4; ++f) {                                           \
          af[f]  = *reinterpret_cast<const bf16x8*>(sA + (wr + 16 * f + l16) * 64 + ks + quad * 8); \
          bfr[f] = *reinterpret_cast<const bf16x8*>(sB + (wc + 16 * f + l16) * 64 + ks + quad * 8); \
        }                                                                       \
        _Pragma("unroll")                                                       \
        for (int fr = 0; fr < 4; ++fr)                                          \
          _Pragma("unroll")                                                     \
          for (int fc = 0; fc < 4; ++fc)                                        \
            acc[fr][fc] = __builtin_amdgcn_mfma_f32_16x16x32_bf16(af[fr], bfr[fc], acc[fr][fc], 0, 0, 0); \
      }                                                                         \
      __syncthreads();                                                          \
    }                                                                           \
  }

// Pass 1: G2 tile + row top-10 partials (RL) + col top-10 partials (LR).
// rowp[row][coltile][10] f16 ; colp[col][rowtile][10] f16 (sorted desc).
// coltile < SC additionally dumps the fp16 tile to sim (row-major, width
// SC*BN) so pass 2 over those columns is a streaming scan.
__global__ __launch_bounds__(256) void gemm_topk(const u16* __restrict__ A,
                                                 const u16* __restrict__ B,
                                                 f16* __restrict__ rowp,
                                                 f16* __restrict__ colp,
                                                 f16* __restrict__ sim,
                                                 int SC) {
  __shared__ __align__(16) u16 smem[17408];  // 34816 B (epi fp16 view 128x136)
  u16* sA = smem;
  u16* sB = smem + 8192;
  DECODE_TILE(0)
  GEMM_K_LOOP(sA, sB)

  // fp16 dump [128][136]
  f16* hC = reinterpret_cast<f16*>(smem);
  #pragma unroll
  for (int fr = 0; fr < 4; ++fr)
    #pragma unroll
    for (int fc = 0; fc < 4; ++fc)
      #pragma unroll
      for (int reg = 0; reg < 4; ++reg)
        hC[(wr + 16 * fr + quad * 4 + reg) * 136 + wc + 16 * fc + l16] =
            (f16)acc[fr][fc][reg];
  __syncthreads();
  // global sim store (stored columns only): 8 iters x 256 thr x 8 f16
  if (coltile < SC) {
    const int SW = SC * BN;
    f16* gs = sim + (size_t)rowbase * SW + colbase;
    #pragma unroll
    for (int itw = 0; itw < 8; ++itw) {
      int idx2 = itw * 2048 + tid * 8;
      int rr = idx2 >> 7, cc = idx2 & 127;
      f16x8 v = *reinterpret_cast<const f16x8*>(hC + rr * 136 + cc);
      *reinterpret_cast<f16x8*>(gs + (size_t)rr * SW + cc) = v;
    }
  }
  // ---- packed row scan: thread owns (row = tid>>1, col-half = tid&1);
  // lo half = even cols, hi half = odd cols of this row-half.
  uint32_t trow[10];
  #pragma unroll
  for (int j = 0; j < 10; ++j) trow[j] = 0xFBFFFBFFu;  // -65504 packed
  {
    const u16* q = reinterpret_cast<const u16*>(hC) + (tid >> 1) * 136 + (tid & 1) * 64;
    #pragma unroll
    for (int c8 = 0; c8 < 8; ++c8) {
      uint4 ch = *reinterpret_cast<const uint4*>(q + c8 * 8);
      pins10(trow, ch.x);
      pins10(trow, ch.y);
      pins10(trow, ch.z);
      pins10(trow, ch.w);
    }
  }
  // ---- packed col scan: thread owns col-pair cp = tid&63 (cols 2cp,2cp+1),
  // row-quarter rq = tid>>6 (32 rows). lo half = col 2cp, hi = col 2cp+1.
  uint32_t tcol[10];
  #pragma unroll
  for (int j = 0; j < 10; ++j) tcol[j] = 0xFBFFFBFFu;
  const int cp = tid & 63, rq = tid >> 6;
  {
    const u16* base = reinterpret_cast<const u16*>(hC) + rq * 32 * 136 + 2 * cp;
    #pragma unroll 8
    for (int i = 0; i < 32; ++i) {
      uint32_t v = *reinterpret_cast<const uint32_t*>(base + i * 136);
      pins10(tcol, v);
    }
  }
  __syncthreads();
  uint32_t* sPk = reinterpret_cast<uint32_t*>(smem);
  // merge col quarters -> colp : lists [64 cp][4 rq][10] u32
  #pragma unroll
  for (int j = 0; j < 10; ++j) sPk[(cp * 4 + rq) * 10 + j] = tcol[j];
  __syncthreads();
  if (tid < 128) {
    float best[10];
    #pragma unroll
    for (int j = 0; j < 10; ++j) best[j] = NEG_INF;
    const int c = tid, cpp = c >> 1, par = c & 1;
    for (int rqi = 0; rqi < 4; ++rqi)
      for (int j = 0; j < 10; ++j) {
        uint32_t u = sPk[(cpp * 4 + rqi) * 10 + j];
        float v = f16bits(par ? (u >> 16) : u);
        if (v > best[9]) ins10(best, v);
        else break;  // list sorted desc
      }
    f16* o = colp + ((size_t)(colbase + c) * NCT + rowtile) * 10;
    #pragma unroll
    for (int j = 0; j < 10; ++j) o[j] = (f16)best[j];
  }
  __syncthreads();
  // merge row halves -> rowp : lists [128 row][2 half][10] u32
  #pragma unroll
  for (int j = 0; j < 10; ++j) sPk[((tid >> 1) * 2 + (tid & 1)) * 10 + j] = trow[j];
  __syncthreads();
  if (tid < 128) {
    float best[10];
    #pragma unroll
    for (int j = 0; j < 10; ++j) best[j] = NEG_INF;
    for (int h = 0; h < 2; ++h)
      for (int par = 0; par < 2; ++par)
        for (int j = 0; j < 10; ++j) {
          uint32_t u = sPk[(tid * 2 + h) * 10 + j];
          float v = f16bits(par ? (u >> 16) : u);
          if (v > best[9]) ins10(best, v);
          else break;
        }
    f16* o = rowp + ((size_t)(rowbase + tid) * NCT + coltile) * 10;
    #pragma unroll
    for (int j = 0; j < 10; ++j) o[j] = (f16)best[j];
  }
}

// Pass 2 (recompute part): tiles with coltile >= ct0.
__global__ __launch_bounds__(256) void gemm_rank(const u16* __restrict__ A,
                                                 const u16* __restrict__ B,
                                                 const float* __restrict__ p,
                                                 const float* __restrict__ thr,
                                                 int* __restrict__ cnt_out,
                                                 float* __restrict__ mx_out,
                                                 int ct0) {
  __shared__ __align__(16) u16 smem[16384];  // 32768 B
  u16* sA = smem;
  u16* sB = smem + 8192;
  DECODE_TILE(ct0)

  float thrv[16];
  #pragma unroll
  for (int i = 0; i < 16; ++i)
    thrv[i] = thr[rowbase + wr + 16 * (i >> 2) + quad * 4 + (i & 3)];
  float pv[4];
  #pragma unroll
  for (int fc = 0; fc < 4; ++fc) pv[fc] = p[colbase + wc + 16 * fc + l16];

  GEMM_K_LOOP(sA, sB)

  int cnt[16];
  float mx[16];
  #pragma unroll
  for (int i = 0; i < 16; ++i) { cnt[i] = 0; mx[i] = NEG_INF; }
  #pragma unroll
  for (int fc = 0; fc < 4; ++fc)
    #pragma unroll
    for (int fr = 0; fr < 4; ++fr)
      #pragma unroll
      for (int reg = 0; reg < 4; ++reg) {
        float t2 = 2.f * acc[fr][fc][reg] - pv[fc];
        int idx2 = fr * 4 + reg;
        cnt[idx2] += (t2 > thrv[idx2]) ? 1 : 0;
        mx[idx2] = fmaxf(mx[idx2], t2);
      }

  // reduce across 16 col-lanes, then combine the two col-half waves per row
  float* sMx = reinterpret_cast<float*>(smem);        // [4][64]
  int*   sCn = reinterpret_cast<int*>(smem) + 256;    // [4][64]
  #pragma unroll
  for (int idx2 = 0; idx2 < 16; ++idx2) {
    int c = cnt[idx2];
    float m = mx[idx2];
    #pragma unroll
    for (int off = 1; off < 16; off <<= 1) {
      c += __shfl_xor(c, off);
      m = fmaxf(m, __shfl_xor(m, off));
    }
    if (l16 == 0) {
      int rloc = 16 * (idx2 >> 2) + quad * 4 + (idx2 & 3);
      sMx[w * 64 + rloc] = m;
      sCn[w * 64 + rloc] = c;
    }
  }
  __syncthreads();
  if (tid < 128) {
    int half = tid >> 6, rloc = tid & 63;
    int c = sCn[(half * 2) * 64 + rloc] + sCn[(half * 2 + 1) * 64 + rloc];
    float m = fmaxf(sMx[(half * 2) * 64 + rloc], sMx[(half * 2 + 1) * 64 + rloc]);
    cnt_out[(size_t)(rowbase + tid) * NCT + coltile] = c;
    mx_out[(size_t)(rowbase + tid) * NCT + coltile] = m;
  }
}

// Pass 2 (stored part): streaming scan of fp16 sim (width SW = SC*BN).
// 4 rows per block; writes one partial count/max per row.
__global__ __launch_bounds__(256) void scan_kernel(const f16* __restrict__ sim,
                                                   const float* __restrict__ p,
                                                   const float* __restrict__ thr,
                                                   int SC,
                                                   int* __restrict__ cnt_s,
                                                   float* __restrict__ mx_s) {
  const int tid = threadIdx.x;
  const int row0 = blockIdx.x * 4;
  const int SW = SC * BN;
  const int nit = SW >> 11;  // SW / 2048 (SC multiple of 16)
  float t[4];
  #pragma unroll
  for (int r = 0; r < 4; ++r) t[r] = thr[row0 + r];
  int cnt[4] = {0, 0, 0, 0};
  float m[4] = {NEG_INF, NEG_INF, NEG_INF, NEG_INF};
  for (int it = 0; it < nit; ++it) {
    int c0 = it * 2048 + tid * 8;
    float pv[8];
    {
      const float4* p4 = reinterpret_cast<const float4*>(p + c0);
      float4 a = p4[0], b = p4[1];
      pv[0] = a.x; pv[1] = a.y; pv[2] = a.z; pv[3] = a.w;
      pv[4] = b.x; pv[5] = b.y; pv[6] = b.z; pv[7] = b.w;
    }
    #pragma unroll
    for (int r = 0; r < 4; ++r) {
      f16x8 v8 = *reinterpret_cast<const f16x8*>(sim + (size_t)(row0 + r) * SW + c0);
      #pragma unroll
      for (int j = 0; j < 8; ++j) {
        float t2 = 2.f * (float)v8[j] - pv[j];
        cnt[r] += (t2 > t[r]) ? 1 : 0;
        m[r] = fmaxf(m[r], t2);
      }
    }
  }
  __shared__ float sM[4][4];
  __shared__ int sC[4][4];
  const int lane = tid & 63, w = tid >> 6;
  #pragma unroll
  for (int r = 0; r < 4; ++r) {
    int c = cnt[r];
    float mm = m[r];
    #pragma unroll
    for (int off = 32; off > 0; off >>= 1) {
      c += __shfl_down(c, off);
      mm = fmaxf(mm, __shfl_down(mm, off));
    }
    if (lane == 0) { sC[r][w] = c; sM[r][w] = mm; }
  }
  __syncthreads();
  if (tid < 4) {
    int c = sC[tid][0] + sC[tid][1] + sC[tid][2] + sC[tid][3];
    float mm = fmaxf(fmaxf(sM[tid][0], sM[tid][1]), fmaxf(sM[tid][2], sM[tid][3]));
    cnt_s[row0 + tid] = c;
    mx_s[row0 + tid] = mm;
  }
}

// p[l] = mean(top10 of rowp[l][*]) + mean(top10 of colp[l][*]); thr = 2*diag - p
__global__ __launch_bounds__(256) void p_kernel(const f16* __restrict__ rowp,
                                                const f16* __restrict__ colp,
                                                const float* __restrict__ diag,
                                                float* __restrict__ pout,
                                                float* __restrict__ throut) {
  int l = blockIdx.x * 256 + threadIdx.x;
  float b1[10], b2[10];
  #pragma unroll
  for (int j = 0; j < 10; ++j) { b1[j] = NEG_INF; b2[j] = NEG_INF; }
  for (int s = 0; s < NCT; ++s) {
    const f16* q1 = rowp + ((size_t)l * NCT + s) * 10;
    for (int j = 0; j < 10; ++j) {   // sorted desc -> early break
      float v = (float)q1[j];
      if (v > b1[9]) ins10(b1, v); else break;
    }
    const f16* q2 = colp + ((size_t)l * NCT + s) * 10;
    for (int j = 0; j < 10; ++j) {
      float v = (float)q2[j];
      if (v > b2[9]) ins10(b2, v); else break;
    }
  }
  float s1 = 0.f, s2 = 0.f;
  #pragma unroll
  for (int j = 0; j < 10; ++j) { s1 += b1[j]; s2 += b2[j]; }
  float pv = (s1 + s2) * 0.1f;
  pout[l] = pv;
  throut[l] = 2.f * diag[l] - pv;
}

// Combine scan partial (stored cols) + per-coltile partials (recomputed cols).
__global__ __launch_bounds__(256) void final_kernel(const int* __restrict__ cnt,
                                                    const float* __restrict__ mx,
                                                    const int* __restrict__ cnt_s,
                                                    const float* __restrict__ mx_s,
                                                    int sc,
                                                    float* __restrict__ out) {
  int r = blockIdx.x * 256 + threadIdx.x;
  int c = 0;
  float m = NEG_INF;
  if (sc > 0) { c = cnt_s[r]; m = mx_s[r]; }
  for (int s = sc; s < NCT; ++s) {
    c += cnt[(size_t)r * NCT + s];
    m = fmaxf(m, mx[(size_t)r * NCT + s]);
  }
  out[r] = (float)c;   // rank of the diagonal element (count strictly greater)
  out[NN + r] = m;     // top-1 csls value
}

extern "C" void kernel_launch(void* const* d_in, const int* in_sizes, int n_in,
                              void* d_out, int out_size, void* d_ws, size_t ws_size,
                              hipStream_t stream) {
  const float* L = (const float*)d_in[0];
  const float* R = (const float*)d_in[1];
  char* ws = (char*)d_ws;

  const size_t PARTB = (size_t)NN * NCT * 10 * 2;               // 40 MiB per partial
  const size_t SIMOFF = (32ull << 20) + 2 * PARTB + (1ull << 20);  // 113 MiB

  u16* Lb   = (u16*)ws;                                 // 16 MiB
  u16* Rb   = (u16*)(ws + (16ull << 20));               // 16 MiB
  f16* rowp = (f16*)(ws + (32ull << 20));               // 40 MiB
  f16* colp = (f16*)(ws + (32ull << 20) + PARTB);       // 40 MiB
  char* tail = ws + (32ull << 20) + 2 * PARTB;          // 1 MiB of small arrays
  float* diag   = (float*)tail;
  float* pbuf   = (float*)(tail + (64ull << 10));
  float* thrbuf = (float*)(tail + (128ull << 10));
  int*   cnt_s  = (int*)(tail + (192ull << 10));
  float* mx_s   = (float*)(tail + (256ull << 10));
  f16*   sim    = (f16*)(ws + SIMOFF);
  // cnt/mx alias colp's region (colp fully consumed by p_kernel first)
  int*   cntp = (int*)colp;                             // 8.4 MB
  float* mxp  = (float*)((char*)colp + (20ull << 20));  // 8.4 MB

  // Stored column-tiles: as many as the workspace holds (multiple of 16).
  int SC = 0;
  if (ws_size > SIMOFF) {
    size_t avail = ws_size - SIMOFF;
    size_t sc = avail / ((size_t)NN * BN * 2);          // 4 MiB per coltile
    if (sc > 128) sc = 128;
    SC = (int)(sc & ~(size_t)15);
  }

  // 1) fp32 -> bf16 casts
  cast_kernel<<<(NN * DD / (256 * 8)), 256, 0, stream>>>(L, Lb);
  cast_kernel<<<(NN * DD / (256 * 8)), 256, 0, stream>>>(R, Rb);
  // 2) diagonal sim values
  diag_kernel<<<NN / 4, 256, 0, stream>>>(Lb, Rb, diag);
  // 3) pass 1 over G2 = R*L^T: top-10 partials + sim store for coltile < SC
  gemm_topk<<<(NN / BM) * (NN / BN), 256, 0, stream>>>(Rb, Lb, rowp, colp, sim, SC);
  // 4) merge partials -> p, thr
  p_kernel<<<NN / 256, 256, 0, stream>>>(rowp, colp, diag, pbuf, thrbuf);
  // 5a) stored columns: streaming scan
  if (SC > 0)
    scan_kernel<<<NN / 4, 256, 0, stream>>>(sim, pbuf, thrbuf, SC, cnt_s, mx_s);
  // 5b) remaining columns: recompute GEMM + rank
  if (SC < 128)
    gemm_rank<<<(NN / BM) * (128 - SC), 256, 0, stream>>>(Rb, Lb, pbuf, thrbuf,
                                                          cntp, mxp, SC);
  // 6) combine -> outputs
  final_kernel<<<NN / 256, 256, 0, stream>>>(cntp, mxp, cnt_s, mx_s, SC,
                                             (float*)d_out);
}

// Round 3
// 994.642 us; speedup vs baseline: 1.7126x; 1.3835x over previous
//
#include <hip/hip_runtime.h>
#include <hip/hip_bf16.h>
#include <stdint.h>

// Problem constants (fixed by setup_inputs)
#define NN 16384
#define DD 512
#define BM 128
#define BN 128
#define BK 64
#define NCT 128       // column tiles (= NN/BN) = per-row partial segments
#define KT 6          // per-tile top-k kept (global top-10 from 128x top-6)
#define NEG_INF (-3.0e38f)

// R11: (a) T2 XOR-swizzle of A/B LDS tiles (pre-swizzled global src +
// swizzled ds_read slot) — kills the 16-way fragment-read conflict
// (SQ_LDS_BANK_CONFLICT 1.15e8 -> expect <4e7). (b) per-tile top-6 packed
// scans (pins6): -40% epilogue VALU, partials 84->50 MB, frees 33 MiB ->
// SC 32->43 stored coltiles, gemm_rank 96->85 tiles. (c) transposed
// partials [seg][entity][6] -> coalesced p_kernel.

typedef unsigned short u16;
typedef _Float16 f16;
typedef __attribute__((ext_vector_type(8))) __bf16 bf16x8;   // MFMA A/B operand
typedef __attribute__((ext_vector_type(8))) short sh8;       // 16B vector
typedef __attribute__((ext_vector_type(8))) _Float16 f16x8;  // 16B of fp16
typedef __attribute__((ext_vector_type(4))) float f32x4;     // MFMA C/D

__device__ __forceinline__ u16 f2bf(float f) {  // RNE fp32->bf16
  uint32_t x = __float_as_uint(f);
  x += 0x7fffu + ((x >> 16) & 1u);
  return (u16)(x >> 16);
}
__device__ __forceinline__ float bf2f(u16 u) {
  return __uint_as_float(((uint32_t)u) << 16);
}
__device__ __forceinline__ float f16bits(uint32_t bits) {  // low 16b as f16
  f16 h;
  u16 b = (u16)bits;
  __builtin_memcpy(&h, &b, 2);
  return (float)h;
}
__device__ __forceinline__ u16 h2bits(f16 h) {
  u16 b;
  __builtin_memcpy(&b, &h, 2);
  return b;
}
__device__ __forceinline__ uint32_t pk_max16(uint32_t a, uint32_t b) {
  uint32_t d;
  asm("v_pk_max_f16 %0, %1, %2" : "=v"(d) : "v"(a), "v"(b));
  return d;
}
__device__ __forceinline__ uint32_t pk_min16(uint32_t a, uint32_t b) {
  uint32_t d;
  asm("v_pk_min_f16 %0, %1, %2" : "=v"(d) : "v"(a), "v"(b));
  return d;
}

// async global->LDS, 16B per lane; lds base wave-uniform.
__device__ __forceinline__ void gload_lds16(const u16* g, u16* lds) {
  __builtin_amdgcn_global_load_lds(
      (const __attribute__((address_space(1))) uint32_t*)g,
      (__attribute__((address_space(3))) uint32_t*)lds,
      16, 0, 0);
}

// Insert v into descending-sorted N-element register array (fp32).
template <int N>
__device__ __forceinline__ void insN(float (&t)[N], float v) {
  #pragma unroll
  for (int j = 0; j < N; ++j) {
    float hi = fmaxf(t[j], v);
    v = fminf(t[j], v);
    t[j] = hi;
  }
}
// Packed variant: two independent sorted-desc f16 lists in lo/hi halves.
template <int N>
__device__ __forceinline__ void pinsN(uint32_t (&t)[N], uint32_t v) {
  #pragma unroll
  for (int j = 0; j < N; ++j) {
    uint32_t hi = pk_max16(t[j], v);
    v = pk_min16(t[j], v);
    t[j] = hi;
  }
}

__global__ __launch_bounds__(256) void cast_kernel(const float* __restrict__ src,
                                                   u16* __restrict__ dst) {
  int i = (blockIdx.x * 256 + threadIdx.x) * 8;
  const float4* s4 = reinterpret_cast<const float4*>(src + i);
  float4 a = s4[0], b = s4[1];
  sh8 o;
  o[0] = (short)f2bf(a.x); o[1] = (short)f2bf(a.y);
  o[2] = (short)f2bf(a.z); o[3] = (short)f2bf(a.w);
  o[4] = (short)f2bf(b.x); o[5] = (short)f2bf(b.y);
  o[6] = (short)f2bf(b.z); o[7] = (short)f2bf(b.w);
  *reinterpret_cast<sh8*>(dst + i) = o;
}

// diag[r] = <Lb_r, Rb_r> — one wave per row
__global__ __launch_bounds__(256) void diag_kernel(const u16* __restrict__ Lb,
                                                   const u16* __restrict__ Rb,
                                                   float* __restrict__ diag) {
  int r = blockIdx.x * 4 + (threadIdx.x >> 6);
  int lane = threadIdx.x & 63;
  sh8 a = *reinterpret_cast<const sh8*>(Lb + (size_t)r * DD + lane * 8);
  sh8 b = *reinterpret_cast<const sh8*>(Rb + (size_t)r * DD + lane * 8);
  float s = 0.f;
  #pragma unroll
  for (int j = 0; j < 8; ++j) s += bf2f((u16)a[j]) * bf2f((u16)b[j]);
  #pragma unroll
  for (int off = 32; off > 0; off >>= 1) s += __shfl_down(s, off);
  if (lane == 0) diag[r] = s;
}

// Shared block-coordinate decode. xcd = blk&7 -> fixed 16-rowtile A-band per
// XCD; coltile sweeps slowly. ct0 = coltile offset (hybrid gemm_rank).
#define DECODE_TILE(ct0)                                \
  const int xcd = blockIdx.x & 7;                       \
  const int idx = blockIdx.x >> 3;                      \
  const int rowtile = xcd * 16 + (idx & 15);            \
  const int coltile = (ct0) + (idx >> 4);               \
  const int rowbase = rowtile * BM;                     \
  const int colbase = coltile * BN;                     \
  const int tid = threadIdx.x;                          \
  const int w = tid >> 6;                               \
  const int lane = tid & 63;                            \
  const int quad = lane >> 4;                           \
  const int l16 = lane & 15;                            \
  const int l7 = l16 & 7;                               \
  const int wr = (w >> 1) * 64;                         \
  const int wc = (w & 1) * 64;                          \
  const int lrow8 = lane >> 3;                          \
  const int gran = lane & 7;

// LDS layout is XOR-swizzled per row: granule slot g' = g ^ (row&7).
// global_load_lds writes linearly -> achieve swizzle by fetching global
// granule (gran ^ lrow8) into linear slot gran (rule #21: both sides).
#define GEMM_K_LOOP(sA, sB)                                                     \
  f32x4 acc[4][4];                                                              \
  _Pragma("unroll")                                                             \
  for (int a_ = 0; a_ < 4; ++a_)                                                \
    _Pragma("unroll")                                                           \
    for (int b_ = 0; b_ < 4; ++b_) acc[a_][b_] = (f32x4){0.f, 0.f, 0.f, 0.f};   \
  {                                                                             \
    const u16* gA = A + (size_t)(rowbase + w * 32 + lrow8) * DD + (gran ^ lrow8) * 8; \
    const u16* gB = B + (size_t)(colbase + w * 32 + lrow8) * DD + (gran ^ lrow8) * 8; \
    for (int kk = 0; kk < DD; kk += BK) {                                       \
      _Pragma("unroll")                                                         \
      for (int it = 0; it < 4; ++it) {                                          \
        gload_lds16(gA + (size_t)it * 8 * DD + kk, sA + (w * 32 + it * 8) * 64);\
        gload_lds16(gB + (size_t)it * 8 * DD + kk, sB + (w * 32 + it * 8) * 64);\
      }                                                                         \
      __syncthreads();                                                          \
      _Pragma("unroll")                                                         \
      for (int ks = 0; ks < BK; ks += 32) {                                     \
        const int slot = (((ks >> 3) + quad) ^ l7) * 8;                         \
        bf16x8 af[4], bfr[4];                                                   \
        _Pragma("unroll")                                                       \
        for (int f = 0; f < 4; ++f) {                                           \
          af[f]  = *reinterpret_cast<const bf16x8*>(sA + (wr + 16 * f + l16) * 64 + slot); \
          bfr[f] = *reinterpret_cast<const bf16x8*>(sB + (wc + 16 * f + l16) * 64 + slot); \
        }                                                                       \
        _Pragma("unroll")                                                       \
        for (int fr = 0; fr < 4; ++fr)                                          \
          _Pragma("unroll")                                                     \
          for (int fc = 0; fc < 4; ++fc)                                        \
            acc[fr][fc] = __builtin_amdgcn_mfma_f32_16x16x32_bf16(af[fr], bfr[fc], acc[fr][fc], 0, 0, 0); \
      }                                                                         \
      __syncthreads();                                                          \
    }                                                                           \
  }

// Pass 1: G2 tile + row top-6 partials (RL) + col top-6 partials (LR).
// rowp[coltile][row][6] f16 ; colp[rowtile][col][6] f16 (sorted desc).
// coltile < SC additionally dumps the fp16 tile to sim (row-major, width
// SC*BN) so pass 2 over those columns is a streaming scan.
__global__ __launch_bounds__(256) void gemm_topk(const u16* __restrict__ A,
                                                 const u16* __restrict__ B,
                                                 f16* __restrict__ rowp,
                                                 f16* __restrict__ colp,
                                                 f16* __restrict__ sim,
                                                 int SC) {
  __shared__ __align__(16) u16 smem[17408];  // 34816 B (epi fp16 view 128x136)
  u16* sA = smem;
  u16* sB = smem + 8192;
  DECODE_TILE(0)
  GEMM_K_LOOP(sA, sB)

  // fp16 dump [128][136]
  f16* hC = reinterpret_cast<f16*>(smem);
  #pragma unroll
  for (int fr = 0; fr < 4; ++fr)
    #pragma unroll
    for (int fc = 0; fc < 4; ++fc)
      #pragma unroll
      for (int reg = 0; reg < 4; ++reg)
        hC[(wr + 16 * fr + quad * 4 + reg) * 136 + wc + 16 * fc + l16] =
            (f16)acc[fr][fc][reg];
  __syncthreads();
  // global sim store (stored columns only): 8 iters x 256 thr x 8 f16
  if (coltile < SC) {
    const int SW = SC * BN;
    f16* gs = sim + (size_t)rowbase * SW + colbase;
    #pragma unroll
    for (int itw = 0; itw < 8; ++itw) {
      int idx2 = itw * 2048 + tid * 8;
      int rr = idx2 >> 7, cc = idx2 & 127;
      f16x8 v = *reinterpret_cast<const f16x8*>(hC + rr * 136 + cc);
      *reinterpret_cast<f16x8*>(gs + (size_t)rr * SW + cc) = v;
    }
  }
  // ---- packed row scan: thread owns (row = tid>>1, col-half = tid&1);
  // lo half = even cols, hi half = odd cols of this row-half.
  uint32_t trow[KT];
  #pragma unroll
  for (int j = 0; j < KT; ++j) trow[j] = 0xFBFFFBFFu;  // -65504 packed
  {
    const u16* q = reinterpret_cast<const u16*>(hC) + (tid >> 1) * 136 + (tid & 1) * 64;
    #pragma unroll
    for (int c8 = 0; c8 < 8; ++c8) {
      uint4 ch = *reinterpret_cast<const uint4*>(q + c8 * 8);
      pinsN<KT>(trow, ch.x);
      pinsN<KT>(trow, ch.y);
      pinsN<KT>(trow, ch.z);
      pinsN<KT>(trow, ch.w);
    }
  }
  // ---- packed col scan: thread owns col-pair cp = tid&63 (cols 2cp,2cp+1),
  // row-quarter rq = tid>>6 (32 rows). lo half = col 2cp, hi = col 2cp+1.
  uint32_t tcol[KT];
  #pragma unroll
  for (int j = 0; j < KT; ++j) tcol[j] = 0xFBFFFBFFu;
  const int cp = tid & 63, rq = tid >> 6;
  {
    const u16* base = reinterpret_cast<const u16*>(hC) + rq * 32 * 136 + 2 * cp;
    #pragma unroll 8
    for (int i = 0; i < 32; ++i) {
      uint32_t v = *reinterpret_cast<const uint32_t*>(base + i * 136);
      pinsN<KT>(tcol, v);
    }
  }
  __syncthreads();
  // write both list sets (disjoint smem regions), one barrier, merge both
  uint32_t* sCl = reinterpret_cast<uint32_t*>(smem);         // [64cp][4rq][KT]
  uint32_t* sRl = reinterpret_cast<uint32_t*>(smem) + 64 * 4 * KT;  // [128][2][KT]
  #pragma unroll
  for (int j = 0; j < KT; ++j) sCl[(cp * 4 + rq) * KT + j] = tcol[j];
  #pragma unroll
  for (int j = 0; j < KT; ++j) sRl[((tid >> 1) * 2 + (tid & 1)) * KT + j] = trow[j];
  __syncthreads();
  if (tid < 128) {
    // col merge -> colp[rowtile][colbase+tid][KT]
    float best[KT];
    #pragma unroll
    for (int j = 0; j < KT; ++j) best[j] = NEG_INF;
    const int cpp = tid >> 1, par = tid & 1;
    for (int rqi = 0; rqi < 4; ++rqi)
      for (int j = 0; j < KT; ++j) {
        uint32_t u = sCl[(cpp * 4 + rqi) * KT + j];
        float v = f16bits(par ? (u >> 16) : u);
        if (v > best[KT - 1]) insN<KT>(best, v);
        else break;  // list sorted desc
      }
    f16* o = colp + ((size_t)rowtile * NN + colbase + tid) * KT;
    uint32_t w0 = h2bits((f16)best[0]) | ((uint32_t)h2bits((f16)best[1]) << 16);
    uint32_t w1 = h2bits((f16)best[2]) | ((uint32_t)h2bits((f16)best[3]) << 16);
    uint32_t w2 = h2bits((f16)best[4]) | ((uint32_t)h2bits((f16)best[5]) << 16);
    uint32_t* o32 = reinterpret_cast<uint32_t*>(o);
    o32[0] = w0; o32[1] = w1; o32[2] = w2;
  } else {
    // row merge -> rowp[coltile][rowbase+t][KT]
    const int t = tid - 128;
    float best[KT];
    #pragma unroll
    for (int j = 0; j < KT; ++j) best[j] = NEG_INF;
    for (int h = 0; h < 2; ++h)
      for (int par = 0; par < 2; ++par)
        for (int j = 0; j < KT; ++j) {
          uint32_t u = sRl[(t * 2 + h) * KT + j];
          float v = f16bits(par ? (u >> 16) : u);
          if (v > best[KT - 1]) insN<KT>(best, v);
          else break;
        }
    f16* o = rowp + ((size_t)coltile * NN + rowbase + t) * KT;
    uint32_t w0 = h2bits((f16)best[0]) | ((uint32_t)h2bits((f16)best[1]) << 16);
    uint32_t w1 = h2bits((f16)best[2]) | ((uint32_t)h2bits((f16)best[3]) << 16);
    uint32_t w2 = h2bits((f16)best[4]) | ((uint32_t)h2bits((f16)best[5]) << 16);
    uint32_t* o32 = reinterpret_cast<uint32_t*>(o);
    o32[0] = w0; o32[1] = w1; o32[2] = w2;
  }
}

// Pass 2 (recompute part): tiles with coltile >= ct0.
__global__ __launch_bounds__(256) void gemm_rank(const u16* __restrict__ A,
                                                 const u16* __restrict__ B,
                                                 const float* __restrict__ p,
                                                 const float* __restrict__ thr,
                                                 int* __restrict__ cnt_out,
                                                 float* __restrict__ mx_out,
                                                 int ct0) {
  __shared__ __align__(16) u16 smem[16384];  // 32768 B
  u16* sA = smem;
  u16* sB = smem + 8192;
  DECODE_TILE(ct0)

  float thrv[16];
  #pragma unroll
  for (int i = 0; i < 16; ++i)
    thrv[i] = thr[rowbase + wr + 16 * (i >> 2) + quad * 4 + (i & 3)];
  float pv[4];
  #pragma unroll
  for (int fc = 0; fc < 4; ++fc) pv[fc] = p[colbase + wc + 16 * fc + l16];

  GEMM_K_LOOP(sA, sB)

  int cnt[16];
  float mx[16];
  #pragma unroll
  for (int i = 0; i < 16; ++i) { cnt[i] = 0; mx[i] = NEG_INF; }
  #pragma unroll
  for (int fc = 0; fc < 4; ++fc)
    #pragma unroll
    for (int fr = 0; fr < 4; ++fr)
      #pragma unroll
      for (int reg = 0; reg < 4; ++reg) {
        float t2 = 2.f * acc[fr][fc][reg] - pv[fc];
        int idx2 = fr * 4 + reg;
        cnt[idx2] += (t2 > thrv[idx2]) ? 1 : 0;
        mx[idx2] = fmaxf(mx[idx2], t2);
      }

  // reduce across 16 col-lanes, then combine the two col-half waves per row
  float* sMx = reinterpret_cast<float*>(smem);        // [4][64]
  int*   sCn = reinterpret_cast<int*>(smem) + 256;    // [4][64]
  #pragma unroll
  for (int idx2 = 0; idx2 < 16; ++idx2) {
    int c = cnt[idx2];
    float m = mx[idx2];
    #pragma unroll
    for (int off = 1; off < 16; off <<= 1) {
      c += __shfl_xor(c, off);
      m = fmaxf(m, __shfl_xor(m, off));
    }
    if (l16 == 0) {
      int rloc = 16 * (idx2 >> 2) + quad * 4 + (idx2 & 3);
      sMx[w * 64 + rloc] = m;
      sCn[w * 64 + rloc] = c;
    }
  }
  __syncthreads();
  if (tid < 128) {
    int half = tid >> 6, rloc = tid & 63;
    int c = sCn[(half * 2) * 64 + rloc] + sCn[(half * 2 + 1) * 64 + rloc];
    float m = fmaxf(sMx[(half * 2) * 64 + rloc], sMx[(half * 2 + 1) * 64 + rloc]);
    cnt_out[(size_t)(rowbase + tid) * NCT + coltile] = c;
    mx_out[(size_t)(rowbase + tid) * NCT + coltile] = m;
  }
}

// Pass 2 (stored part): streaming scan of fp16 sim (width SW = SC*BN).
// 4 rows per block; writes one partial count/max per row.
__global__ __launch_bounds__(256) void scan_kernel(const f16* __restrict__ sim,
                                                   const float* __restrict__ p,
                                                   const float* __restrict__ thr,
                                                   int SC,
                                                   int* __restrict__ cnt_s,
                                                   float* __restrict__ mx_s) {
  const int tid = threadIdx.x;
  const int row0 = blockIdx.x * 4;
  const int SW = SC * BN;
  float t[4];
  #pragma unroll
  for (int r = 0; r < 4; ++r) t[r] = thr[row0 + r];
  int cnt[4] = {0, 0, 0, 0};
  float m[4] = {NEG_INF, NEG_INF, NEG_INF, NEG_INF};
  for (int c0 = tid * 8; c0 < SW; c0 += 2048) {
    float pv[8];
    {
      const float4* p4 = reinterpret_cast<const float4*>(p + c0);
      float4 a = p4[0], b = p4[1];
      pv[0] = a.x; pv[1] = a.y; pv[2] = a.z; pv[3] = a.w;
      pv[4] = b.x; pv[5] = b.y; pv[6] = b.z; pv[7] = b.w;
    }
    #pragma unroll
    for (int r = 0; r < 4; ++r) {
      f16x8 v8 = *reinterpret_cast<const f16x8*>(sim + (size_t)(row0 + r) * SW + c0);
      #pragma unroll
      for (int j = 0; j < 8; ++j) {
        float t2 = 2.f * (float)v8[j] - pv[j];
        cnt[r] += (t2 > t[r]) ? 1 : 0;
        m[r] = fmaxf(m[r], t2);
      }
    }
  }
  __shared__ float sM[4][4];
  __shared__ int sC[4][4];
  const int lane = tid & 63, w = tid >> 6;
  #pragma unroll
  for (int r = 0; r < 4; ++r) {
    int c = cnt[r];
    float mm = m[r];
    #pragma unroll
    for (int off = 32; off > 0; off >>= 1) {
      c += __shfl_down(c, off);
      mm = fmaxf(mm, __shfl_down(mm, off));
    }
    if (lane == 0) { sC[r][w] = c; sM[r][w] = mm; }
  }
  __syncthreads();
  if (tid < 4) {
    int c = sC[tid][0] + sC[tid][1] + sC[tid][2] + sC[tid][3];
    float mm = fmaxf(fmaxf(sM[tid][0], sM[tid][1]), fmaxf(sM[tid][2], sM[tid][3]));
    cnt_s[row0 + tid] = c;
    mx_s[row0 + tid] = mm;
  }
}

// p[l] = mean(top10 of rowp[*][l]) + mean(top10 of colp[*][l]); thr = 2*diag - p
// partials are [seg][entity][KT] -> coalesced lane reads.
__global__ __launch_bounds__(256) void p_kernel(const f16* __restrict__ rowp,
                                                const f16* __restrict__ colp,
                                                const float* __restrict__ diag,
                                                float* __restrict__ pout,
                                                float* __restrict__ throut) {
  int l = blockIdx.x * 256 + threadIdx.x;
  float b1[10], b2[10];
  #pragma unroll
  for (int j = 0; j < 10; ++j) { b1[j] = NEG_INF; b2[j] = NEG_INF; }
  for (int s = 0; s < NCT; ++s) {
    const uint32_t* q1 = reinterpret_cast<const uint32_t*>(rowp + ((size_t)s * NN + l) * KT);
    #pragma unroll
    for (int d = 0; d < 3; ++d) {
      uint32_t u = q1[d];
      float v0 = f16bits(u), v1 = f16bits(u >> 16);
      if (v0 > b1[9]) insN<10>(b1, v0); else break;
      if (v1 > b1[9]) insN<10>(b1, v1); else break;
    }
    const uint32_t* q2 = reinterpret_cast<const uint32_t*>(colp + ((size_t)s * NN + l) * KT);
    #pragma unroll
    for (int d = 0; d < 3; ++d) {
      uint32_t u = q2[d];
      float v0 = f16bits(u), v1 = f16bits(u >> 16);
      if (v0 > b2[9]) insN<10>(b2, v0); else break;
      if (v1 > b2[9]) insN<10>(b2, v1); else break;
    }
  }
  float s1 = 0.f, s2 = 0.f;
  #pragma unroll
  for (int j = 0; j < 10; ++j) { s1 += b1[j]; s2 += b2[j]; }
  float pv = (s1 + s2) * 0.1f;
  pout[l] = pv;
  throut[l] = 2.f * diag[l] - pv;
}

// Combine scan partial (stored cols) + per-coltile partials (recomputed cols).
__global__ __launch_bounds__(256) void final_kernel(const int* __restrict__ cnt,
                                                    const float* __restrict__ mx,
                                                    const int* __restrict__ cnt_s,
                                                    const float* __restrict__ mx_s,
                                                    int sc,
                                                    float* __restrict__ out) {
  int r = blockIdx.x * 256 + threadIdx.x;
  int c = 0;
  float m = NEG_INF;
  if (sc > 0) { c = cnt_s[r]; m = mx_s[r]; }
  for (int s = sc; s < NCT; ++s) {
    c += cnt[(size_t)r * NCT + s];
    m = fmaxf(m, mx[(size_t)r * NCT + s]);
  }
  out[r] = (float)c;   // rank of the diagonal element (count strictly greater)
  out[NN + r] = m;     // top-1 csls value
}

extern "C" void kernel_launch(void* const* d_in, const int* in_sizes, int n_in,
                              void* d_out, int out_size, void* d_ws, size_t ws_size,
                              hipStream_t stream) {
  const float* L = (const float*)d_in[0];
  const float* R = (const float*)d_in[1];
  char* ws = (char*)d_ws;

  const size_t PARTB = (size_t)NN * NCT * KT * 2;       // 24 MiB per partial
  const size_t TAILOFF = (32ull << 20) + 2 * PARTB;     // 80 MiB
  const size_t SIMOFF = TAILOFF + (320ull << 10);       // 80.3125 MiB

  u16* Lb   = (u16*)ws;                                 // 16 MiB
  u16* Rb   = (u16*)(ws + (16ull << 20));               // 16 MiB
  f16* rowp = (f16*)(ws + (32ull << 20));               // 24 MiB [seg][row][KT]
  f16* colp = (f16*)(ws + (32ull << 20) + PARTB);       // 24 MiB [seg][col][KT]
  char* tail = ws + TAILOFF;
  float* diag   = (float*)tail;
  float* pbuf   = (float*)(tail + (64ull << 10));
  float* thrbuf = (float*)(tail + (128ull << 10));
  int*   cnt_s  = (int*)(tail + (192ull << 10));
  float* mx_s   = (float*)(tail + (256ull << 10));
  f16*   sim    = (f16*)(ws + SIMOFF);
  // cnt/mx alias partial regions (fully consumed by p_kernel first)
  int*   cntp = (int*)rowp;                             // 8.4 MB
  float* mxp  = (float*)colp;                           // 8.4 MB

  // Stored column-tiles: as many as the workspace holds (4 MiB each).
  int SC = 0;
  if (ws_size > SIMOFF) {
    size_t sc = (ws_size - SIMOFF) / ((size_t)NN * BN * 2);
    if (sc > 128) sc = 128;
    SC = (int)sc;
  }

  // 1) fp32 -> bf16 casts
  cast_kernel<<<(NN * DD / (256 * 8)), 256, 0, stream>>>(L, Lb);
  cast_kernel<<<(NN * DD / (256 * 8)), 256, 0, stream>>>(R, Rb);
  // 2) diagonal sim values
  diag_kernel<<<NN / 4, 256, 0, stream>>>(Lb, Rb, diag);
  // 3) pass 1 over G2 = R*L^T: top-6 partials + sim store for coltile < SC
  gemm_topk<<<(NN / BM) * (NN / BN), 256, 0, stream>>>(Rb, Lb, rowp, colp, sim, SC);
  // 4) merge partials -> p, thr
  p_kernel<<<NN / 256, 256, 0, stream>>>(rowp, colp, diag, pbuf, thrbuf);
  // 5a) stored columns: streaming scan
  if (SC > 0)
    scan_kernel<<<NN / 4, 256, 0, stream>>>(sim, pbuf, thrbuf, SC, cnt_s, mx_s);
  // 5b) remaining columns: recompute GEMM + rank
  if (SC < 128)
    gemm_rank<<<(NN / BM) * (128 - SC), 256, 0, stream>>>(Rb, Lb, pbuf, thrbuf,
                                                          cntp, mxp, SC);
  // 6) combine -> outputs
  final_kernel<<<NN / 256, 256, 0, stream>>>(cntp, mxp, cnt_s, mx_s, SC,
                                             (float*)d_out);
}

// Round 4
// 855.444 us; speedup vs baseline: 1.9913x; 1.1627x over previous
//
#include <hip/hip_runtime.h>
#include <hip/hip_bf16.h>
#include <stdint.h>

// Problem constants (fixed by setup_inputs)
#define NN 16384
#define DD 512
#define BM 128
#define BN 128
#define NCT 128       // column tiles (= NN/BN) = per-row partial segments
#define KT 6          // per-tile top-k kept (global top-10 from 128x top-6)
#define NEG_INF (-3.0e38f)

// R12: prefetch double-buffered K-loop (T3-minimum + T4 counted vmcnt).
// Old loop: stage -> syncthreads (vmcnt(0) drain!) -> compute: exposes full
// load latency every K-step (MfmaUtil 25%). New: BK=32 dbuf (32 KB, keeps
// 4 blocks/CU), raw s_barrier + s_waitcnt vmcnt(4) so next-tile loads stay
// in flight across the barrier. Row-pair XOR swizzle (8 granules/super-row)
// keeps ds_read_b128 at the conflict-free floor. gemm_rank: thr/p loads
// moved after the K-loop (VGPR liveness fix).

typedef unsigned short u16;
typedef _Float16 f16;
typedef __attribute__((ext_vector_type(8))) __bf16 bf16x8;   // MFMA A/B operand
typedef __attribute__((ext_vector_type(8))) short sh8;       // 16B vector
typedef __attribute__((ext_vector_type(8))) _Float16 f16x8;  // 16B of fp16
typedef __attribute__((ext_vector_type(4))) float f32x4;     // MFMA C/D

__device__ __forceinline__ u16 f2bf(float f) {  // RNE fp32->bf16
  uint32_t x = __float_as_uint(f);
  x += 0x7fffu + ((x >> 16) & 1u);
  return (u16)(x >> 16);
}
__device__ __forceinline__ float bf2f(u16 u) {
  return __uint_as_float(((uint32_t)u) << 16);
}
__device__ __forceinline__ float f16bits(uint32_t bits) {  // low 16b as f16
  f16 h;
  u16 b = (u16)bits;
  __builtin_memcpy(&h, &b, 2);
  return (float)h;
}
__device__ __forceinline__ u16 h2bits(f16 h) {
  u16 b;
  __builtin_memcpy(&b, &h, 2);
  return b;
}
__device__ __forceinline__ uint32_t pk_max16(uint32_t a, uint32_t b) {
  uint32_t d;
  asm("v_pk_max_f16 %0, %1, %2" : "=v"(d) : "v"(a), "v"(b));
  return d;
}
__device__ __forceinline__ uint32_t pk_min16(uint32_t a, uint32_t b) {
  uint32_t d;
  asm("v_pk_min_f16 %0, %1, %2" : "=v"(d) : "v"(a), "v"(b));
  return d;
}

// async global->LDS, 16B per lane; lds base wave-uniform.
__device__ __forceinline__ void gload_lds16(const u16* g, u16* lds) {
  __builtin_amdgcn_global_load_lds(
      (const __attribute__((address_space(1))) uint32_t*)g,
      (__attribute__((address_space(3))) uint32_t*)lds,
      16, 0, 0);
}

// Insert v into descending-sorted N-element register array (fp32).
template <int N>
__device__ __forceinline__ void insN(float (&t)[N], float v) {
  #pragma unroll
  for (int j = 0; j < N; ++j) {
    float hi = fmaxf(t[j], v);
    v = fminf(t[j], v);
    t[j] = hi;
  }
}
// Packed variant: two independent sorted-desc f16 lists in lo/hi halves.
template <int N>
__device__ __forceinline__ void pinsN(uint32_t (&t)[N], uint32_t v) {
  #pragma unroll
  for (int j = 0; j < N; ++j) {
    uint32_t hi = pk_max16(t[j], v);
    v = pk_min16(t[j], v);
    t[j] = hi;
  }
}

__global__ __launch_bounds__(256) void cast_kernel(const float* __restrict__ src,
                                                   u16* __restrict__ dst) {
  int i = (blockIdx.x * 256 + threadIdx.x) * 8;
  const float4* s4 = reinterpret_cast<const float4*>(src + i);
  float4 a = s4[0], b = s4[1];
  sh8 o;
  o[0] = (short)f2bf(a.x); o[1] = (short)f2bf(a.y);
  o[2] = (short)f2bf(a.z); o[3] = (short)f2bf(a.w);
  o[4] = (short)f2bf(b.x); o[5] = (short)f2bf(b.y);
  o[6] = (short)f2bf(b.z); o[7] = (short)f2bf(b.w);
  *reinterpret_cast<sh8*>(dst + i) = o;
}

// diag[r] = <Lb_r, Rb_r> — one wave per row
__global__ __launch_bounds__(256) void diag_kernel(const u16* __restrict__ Lb,
                                                   const u16* __restrict__ Rb,
                                                   float* __restrict__ diag) {
  int r = blockIdx.x * 4 + (threadIdx.x >> 6);
  int lane = threadIdx.x & 63;
  sh8 a = *reinterpret_cast<const sh8*>(Lb + (size_t)r * DD + lane * 8);
  sh8 b = *reinterpret_cast<const sh8*>(Rb + (size_t)r * DD + lane * 8);
  float s = 0.f;
  #pragma unroll
  for (int j = 0; j < 8; ++j) s += bf2f((u16)a[j]) * bf2f((u16)b[j]);
  #pragma unroll
  for (int off = 32; off > 0; off >>= 1) s += __shfl_down(s, off);
  if (lane == 0) diag[r] = s;
}

// Shared block-coordinate decode. xcd = blk&7 -> fixed 16-rowtile A-band per
// XCD; coltile sweeps slowly. ct0 = coltile offset (hybrid gemm_rank).
#define DECODE_TILE(ct0)                                \
  const int xcd = blockIdx.x & 7;                       \
  const int idx = blockIdx.x >> 3;                      \
  const int rowtile = xcd * 16 + (idx & 15);            \
  const int coltile = (ct0) + (idx >> 4);               \
  const int rowbase = rowtile * BM;                     \
  const int colbase = coltile * BN;                     \
  const int tid = threadIdx.x;                          \
  const int w = tid >> 6;                               \
  const int lane = tid & 63;                            \
  const int quad = lane >> 4;                           \
  const int l16 = lane & 15;                            \
  const int wr = (w >> 1) * 64;                         \
  const int wc = (w & 1) * 64;                          \
  (void)xcd; (void)w; (void)lane;

// ---- BK=32 double-buffered prefetch K-loop with counted vmcnt ----
// LDS per K-step per matrix: 128 rows x 32 cols bf16 = 8 KB, stored in
// super-rows rp (=2 rows) of 8 granules (16B each), XOR-swizzled:
// linear slot (rp, g) holds global granule gp = g ^ (rp&7) where
// gp>>2 = row parity, gp&3 = col-granule. Fragment read for (row, quad)
// reads slot g = (((row&1)<<2)|quad) ^ (rp&7) -> 8 lanes per 16B-slot
// class = b128 conflict-free floor. Staging fetches the permuted global
// source into linear LDS (involution, both-sides rule).
#define GEMM_PRE()                                                              \
  const int gl1_ = 256 + tid;                                                   \
  const int rp0_ = tid >> 3, gp0_ = (tid & 7) ^ (rp0_ & 7);                     \
  const int grow0_ = rp0_ * 2 + (gp0_ >> 2), gcol0_ = (gp0_ & 3) * 8;           \
  const int rp1_ = gl1_ >> 3, gp1_ = (gl1_ & 7) ^ (rp1_ & 7);                   \
  const int grow1_ = rp1_ * 2 + (gp1_ >> 2), gcol1_ = (gp1_ & 3) * 8;           \
  const u16* gA0_ = A + (size_t)(rowbase + grow0_) * DD + gcol0_;               \
  const u16* gA1_ = A + (size_t)(rowbase + grow1_) * DD + gcol1_;               \
  const u16* gB0_ = B + (size_t)(colbase + grow0_) * DD + gcol0_;               \
  const u16* gB1_ = B + (size_t)(colbase + grow1_) * DD + gcol1_;               \
  const int gsel_ = ((((l16) & 1) << 2) + quad) ^ (l16 >> 1);                   \
  const int rdA_ = (wr / 2 + (l16 >> 1)) * 64 + gsel_ * 8;                      \
  const int rdB_ = (wc / 2 + (l16 >> 1)) * 64 + gsel_ * 8;

#define STAGE(t, dA, dB)                                                        \
  gload_lds16(gA0_ + (t) * 32, (dA) + tid * 8);                                 \
  gload_lds16(gA1_ + (t) * 32, (dA) + 2048 + tid * 8);                          \
  gload_lds16(gB0_ + (t) * 32, (dB) + tid * 8);                                 \
  gload_lds16(gB1_ + (t) * 32, (dB) + 2048 + tid * 8);

#define GEMM_K_LOOP(sA0_, sA1_, sB0_, sB1_)                                     \
  f32x4 acc[4][4];                                                              \
  _Pragma("unroll")                                                             \
  for (int a_ = 0; a_ < 4; ++a_)                                                \
    _Pragma("unroll")                                                           \
    for (int b_ = 0; b_ < 4; ++b_) acc[a_][b_] = (f32x4){0.f, 0.f, 0.f, 0.f};   \
  {                                                                             \
    GEMM_PRE()                                                                  \
    u16* const bufA_[2] = {(sA0_), (sA1_)};                                     \
    u16* const bufB_[2] = {(sB0_), (sB1_)};                                     \
    STAGE(0, bufA_[0], bufB_[0])                                                \
    STAGE(1, bufA_[1], bufB_[1])                                                \
    _Pragma("unroll")                                                           \
    for (int t = 0; t < 16; ++t) {                                              \
      if (t < 15) { asm volatile("s_waitcnt vmcnt(4)" ::: "memory"); }          \
      else        { asm volatile("s_waitcnt vmcnt(0)" ::: "memory"); }          \
      __builtin_amdgcn_s_barrier();                                             \
      asm volatile("" ::: "memory");                                            \
      {                                                                         \
        const u16* cA_ = bufA_[t & 1];                                          \
        const u16* cB_ = bufB_[t & 1];                                          \
        bf16x8 af[4], bfv[4];                                                   \
        _Pragma("unroll")                                                       \
        for (int f = 0; f < 4; ++f) {                                           \
          af[f]  = *reinterpret_cast<const bf16x8*>(cA_ + rdA_ + f * 512);      \
          bfv[f] = *reinterpret_cast<const bf16x8*>(cB_ + rdB_ + f * 512);      \
        }                                                                       \
        _Pragma("unroll")                                                       \
        for (int fr = 0; fr < 4; ++fr)                                          \
          _Pragma("unroll")                                                     \
          for (int fc = 0; fc < 4; ++fc)                                        \
            acc[fr][fc] = __builtin_amdgcn_mfma_f32_16x16x32_bf16(af[fr], bfv[fc], acc[fr][fc], 0, 0, 0); \
      }                                                                         \
      asm volatile("" ::: "memory");                                            \
      __builtin_amdgcn_s_barrier();                                             \
      if (t + 2 < 16) { STAGE(t + 2, bufA_[t & 1], bufB_[t & 1]) }              \
    }                                                                           \
  }

// Pass 1: G2 tile + row top-6 partials (RL) + col top-6 partials (LR).
// rowp[coltile][row][6] f16 ; colp[rowtile][col][6] f16 (sorted desc).
// coltile < SC additionally dumps the fp16 tile to sim (row-major, width
// SC*BN) so pass 2 over those columns is a streaming scan.
__global__ __launch_bounds__(256) void gemm_topk(const u16* __restrict__ A,
                                                 const u16* __restrict__ B,
                                                 f16* __restrict__ rowp,
                                                 f16* __restrict__ colp,
                                                 f16* __restrict__ sim,
                                                 int SC) {
  __shared__ __align__(16) u16 smem[17408];  // 34816 B (epi fp16 view 128x136)
  u16* sA0 = smem;
  u16* sA1 = smem + 4096;
  u16* sB0 = smem + 8192;
  u16* sB1 = smem + 12288;
  DECODE_TILE(0)
  GEMM_K_LOOP(sA0, sA1, sB0, sB1)

  // fp16 dump [128][136]
  f16* hC = reinterpret_cast<f16*>(smem);
  #pragma unroll
  for (int fr = 0; fr < 4; ++fr)
    #pragma unroll
    for (int fc = 0; fc < 4; ++fc)
      #pragma unroll
      for (int reg = 0; reg < 4; ++reg)
        hC[(wr + 16 * fr + quad * 4 + reg) * 136 + wc + 16 * fc + l16] =
            (f16)acc[fr][fc][reg];
  __syncthreads();
  // global sim store (stored columns only): 8 iters x 256 thr x 8 f16
  if (coltile < SC) {
    const int SW = SC * BN;
    f16* gs = sim + (size_t)rowbase * SW + colbase;
    #pragma unroll
    for (int itw = 0; itw < 8; ++itw) {
      int idx2 = itw * 2048 + tid * 8;
      int rr = idx2 >> 7, cc = idx2 & 127;
      f16x8 v = *reinterpret_cast<const f16x8*>(hC + rr * 136 + cc);
      *reinterpret_cast<f16x8*>(gs + (size_t)rr * SW + cc) = v;
    }
  }
  // ---- packed row scan: thread owns (row = tid>>1, col-half = tid&1);
  // lo half = even cols, hi half = odd cols of this row-half.
  uint32_t trow[KT];
  #pragma unroll
  for (int j = 0; j < KT; ++j) trow[j] = 0xFBFFFBFFu;  // -65504 packed
  {
    const u16* q = reinterpret_cast<const u16*>(hC) + (tid >> 1) * 136 + (tid & 1) * 64;
    #pragma unroll
    for (int c8 = 0; c8 < 8; ++c8) {
      uint4 ch = *reinterpret_cast<const uint4*>(q + c8 * 8);
      pinsN<KT>(trow, ch.x);
      pinsN<KT>(trow, ch.y);
      pinsN<KT>(trow, ch.z);
      pinsN<KT>(trow, ch.w);
    }
  }
  // ---- packed col scan: thread owns col-pair cp = tid&63 (cols 2cp,2cp+1),
  // row-quarter rq = tid>>6 (32 rows). lo half = col 2cp, hi = col 2cp+1.
  uint32_t tcol[KT];
  #pragma unroll
  for (int j = 0; j < KT; ++j) tcol[j] = 0xFBFFFBFFu;
  const int cp = tid & 63, rq = tid >> 6;
  {
    const u16* base = reinterpret_cast<const u16*>(hC) + rq * 32 * 136 + 2 * cp;
    #pragma unroll 8
    for (int i = 0; i < 32; ++i) {
      uint32_t v = *reinterpret_cast<const uint32_t*>(base + i * 136);
      pinsN<KT>(tcol, v);
    }
  }
  __syncthreads();
  // write both list sets (disjoint smem regions), one barrier, merge both
  uint32_t* sCl = reinterpret_cast<uint32_t*>(smem);         // [64cp][4rq][KT]
  uint32_t* sRl = reinterpret_cast<uint32_t*>(smem) + 64 * 4 * KT;  // [128][2][KT]
  #pragma unroll
  for (int j = 0; j < KT; ++j) sCl[(cp * 4 + rq) * KT + j] = tcol[j];
  #pragma unroll
  for (int j = 0; j < KT; ++j) sRl[((tid >> 1) * 2 + (tid & 1)) * KT + j] = trow[j];
  __syncthreads();
  if (tid < 128) {
    // col merge -> colp[rowtile][colbase+tid][KT]
    float best[KT];
    #pragma unroll
    for (int j = 0; j < KT; ++j) best[j] = NEG_INF;
    const int cpp = tid >> 1, par = tid & 1;
    for (int rqi = 0; rqi < 4; ++rqi)
      for (int j = 0; j < KT; ++j) {
        uint32_t u = sCl[(cpp * 4 + rqi) * KT + j];
        float v = f16bits(par ? (u >> 16) : u);
        if (v > best[KT - 1]) insN<KT>(best, v);
        else break;  // list sorted desc
      }
    f16* o = colp + ((size_t)rowtile * NN + colbase + tid) * KT;
    uint32_t w0 = h2bits((f16)best[0]) | ((uint32_t)h2bits((f16)best[1]) << 16);
    uint32_t w1 = h2bits((f16)best[2]) | ((uint32_t)h2bits((f16)best[3]) << 16);
    uint32_t w2 = h2bits((f16)best[4]) | ((uint32_t)h2bits((f16)best[5]) << 16);
    uint32_t* o32 = reinterpret_cast<uint32_t*>(o);
    o32[0] = w0; o32[1] = w1; o32[2] = w2;
  } else {
    // row merge -> rowp[coltile][rowbase+t][KT]
    const int t = tid - 128;
    float best[KT];
    #pragma unroll
    for (int j = 0; j < KT; ++j) best[j] = NEG_INF;
    for (int h = 0; h < 2; ++h)
      for (int par = 0; par < 2; ++par)
        for (int j = 0; j < KT; ++j) {
          uint32_t u = sRl[(t * 2 + h) * KT + j];
          float v = f16bits(par ? (u >> 16) : u);
          if (v > best[KT - 1]) insN<KT>(best, v);
          else break;
        }
    f16* o = rowp + ((size_t)coltile * NN + rowbase + t) * KT;
    uint32_t w0 = h2bits((f16)best[0]) | ((uint32_t)h2bits((f16)best[1]) << 16);
    uint32_t w1 = h2bits((f16)best[2]) | ((uint32_t)h2bits((f16)best[3]) << 16);
    uint32_t w2 = h2bits((f16)best[4]) | ((uint32_t)h2bits((f16)best[5]) << 16);
    uint32_t* o32 = reinterpret_cast<uint32_t*>(o);
    o32[0] = w0; o32[1] = w1; o32[2] = w2;
  }
}

// Pass 2 (recompute part): tiles with coltile >= ct0.
__global__ __launch_bounds__(256) void gemm_rank(const u16* __restrict__ A,
                                                 const u16* __restrict__ B,
                                                 const float* __restrict__ p,
                                                 const float* __restrict__ thr,
                                                 int* __restrict__ cnt_out,
                                                 float* __restrict__ mx_out,
                                                 int ct0) {
  __shared__ __align__(16) u16 smem[16384];  // 32768 B
  u16* sA0 = smem;
  u16* sA1 = smem + 4096;
  u16* sB0 = smem + 8192;
  u16* sB1 = smem + 12288;
  DECODE_TILE(ct0)

  GEMM_K_LOOP(sA0, sA1, sB0, sB1)

  // epilogue-only loads (kept out of the K-loop to save live VGPRs)
  float thrv[16];
  #pragma unroll
  for (int i = 0; i < 16; ++i)
    thrv[i] = thr[rowbase + wr + 16 * (i >> 2) + quad * 4 + (i & 3)];
  float pv[4];
  #pragma unroll
  for (int fc = 0; fc < 4; ++fc) pv[fc] = p[colbase + wc + 16 * fc + l16];

  int cnt[16];
  float mx[16];
  #pragma unroll
  for (int i = 0; i < 16; ++i) { cnt[i] = 0; mx[i] = NEG_INF; }
  #pragma unroll
  for (int fc = 0; fc < 4; ++fc)
    #pragma unroll
    for (int fr = 0; fr < 4; ++fr)
      #pragma unroll
      for (int reg = 0; reg < 4; ++reg) {
        float t2 = 2.f * acc[fr][fc][reg] - pv[fc];
        int idx2 = fr * 4 + reg;
        cnt[idx2] += (t2 > thrv[idx2]) ? 1 : 0;
        mx[idx2] = fmaxf(mx[idx2], t2);
      }

  // reduce across 16 col-lanes, then combine the two col-half waves per row
  float* sMx = reinterpret_cast<float*>(smem);        // [4][64]
  int*   sCn = reinterpret_cast<int*>(smem) + 256;    // [4][64]
  const int wv = tid >> 6;
  #pragma unroll
  for (int idx2 = 0; idx2 < 16; ++idx2) {
    int c = cnt[idx2];
    float m = mx[idx2];
    #pragma unroll
    for (int off = 1; off < 16; off <<= 1) {
      c += __shfl_xor(c, off);
      m = fmaxf(m, __shfl_xor(m, off));
    }
    if (l16 == 0) {
      int rloc = 16 * (idx2 >> 2) + quad * 4 + (idx2 & 3);
      sMx[wv * 64 + rloc] = m;
      sCn[wv * 64 + rloc] = c;
    }
  }
  __syncthreads();
  if (tid < 128) {
    int half = tid >> 6, rloc = tid & 63;
    int c = sCn[(half * 2) * 64 + rloc] + sCn[(half * 2 + 1) * 64 + rloc];
    float m = fmaxf(sMx[(half * 2) * 64 + rloc], sMx[(half * 2 + 1) * 64 + rloc]);
    cnt_out[(size_t)(rowbase + tid) * NCT + coltile] = c;
    mx_out[(size_t)(rowbase + tid) * NCT + coltile] = m;
  }
}

// Pass 2 (stored part): streaming scan of fp16 sim (width SW = SC*BN).
// 4 rows per block; writes one partial count/max per row.
__global__ __launch_bounds__(256) void scan_kernel(const f16* __restrict__ sim,
                                                   const float* __restrict__ p,
                                                   const float* __restrict__ thr,
                                                   int SC,
                                                   int* __restrict__ cnt_s,
                                                   float* __restrict__ mx_s) {
  const int tid = threadIdx.x;
  const int row0 = blockIdx.x * 4;
  const int SW = SC * BN;
  float t[4];
  #pragma unroll
  for (int r = 0; r < 4; ++r) t[r] = thr[row0 + r];
  int cnt[4] = {0, 0, 0, 0};
  float m[4] = {NEG_INF, NEG_INF, NEG_INF, NEG_INF};
  for (int c0 = tid * 8; c0 < SW; c0 += 2048) {
    float pv[8];
    {
      const float4* p4 = reinterpret_cast<const float4*>(p + c0);
      float4 a = p4[0], b = p4[1];
      pv[0] = a.x; pv[1] = a.y; pv[2] = a.z; pv[3] = a.w;
      pv[4] = b.x; pv[5] = b.y; pv[6] = b.z; pv[7] = b.w;
    }
    #pragma unroll
    for (int r = 0; r < 4; ++r) {
      f16x8 v8 = *reinterpret_cast<const f16x8*>(sim + (size_t)(row0 + r) * SW + c0);
      #pragma unroll
      for (int j = 0; j < 8; ++j) {
        float t2 = 2.f * (float)v8[j] - pv[j];
        cnt[r] += (t2 > t[r]) ? 1 : 0;
        m[r] = fmaxf(m[r], t2);
      }
    }
  }
  __shared__ float sM[4][4];
  __shared__ int sC[4][4];
  const int lane = tid & 63, w = tid >> 6;
  #pragma unroll
  for (int r = 0; r < 4; ++r) {
    int c = cnt[r];
    float mm = m[r];
    #pragma unroll
    for (int off = 32; off > 0; off >>= 1) {
      c += __shfl_down(c, off);
      mm = fmaxf(mm, __shfl_down(mm, off));
    }
    if (lane == 0) { sC[r][w] = c; sM[r][w] = mm; }
  }
  __syncthreads();
  if (tid < 4) {
    int c = sC[tid][0] + sC[tid][1] + sC[tid][2] + sC[tid][3];
    float mm = fmaxf(fmaxf(sM[tid][0], sM[tid][1]), fmaxf(sM[tid][2], sM[tid][3]));
    cnt_s[row0 + tid] = c;
    mx_s[row0 + tid] = mm;
  }
}

// p[l] = mean(top10 of rowp[*][l]) + mean(top10 of colp[*][l]); thr = 2*diag - p
// partials are [seg][entity][KT] -> coalesced lane reads.
__global__ __launch_bounds__(256) void p_kernel(const f16* __restrict__ rowp,
                                                const f16* __restrict__ colp,
                                                const float* __restrict__ diag,
                                                float* __restrict__ pout,
                                                float* __restrict__ throut) {
  int l = blockIdx.x * 256 + threadIdx.x;
  float b1[10], b2[10];
  #pragma unroll
  for (int j = 0; j < 10; ++j) { b1[j] = NEG_INF; b2[j] = NEG_INF; }
  for (int s = 0; s < NCT; ++s) {
    const uint32_t* q1 = reinterpret_cast<const uint32_t*>(rowp + ((size_t)s * NN + l) * KT);
    #pragma unroll
    for (int d = 0; d < 3; ++d) {
      uint32_t u = q1[d];
      float v0 = f16bits(u), v1 = f16bits(u >> 16);
      if (v0 > b1[9]) insN<10>(b1, v0); else break;
      if (v1 > b1[9]) insN<10>(b1, v1); else break;
    }
    const uint32_t* q2 = reinterpret_cast<const uint32_t*>(colp + ((size_t)s * NN + l) * KT);
    #pragma unroll
    for (int d = 0; d < 3; ++d) {
      uint32_t u = q2[d];
      float v0 = f16bits(u), v1 = f16bits(u >> 16);
      if (v0 > b2[9]) insN<10>(b2, v0); else break;
      if (v1 > b2[9]) insN<10>(b2, v1); else break;
    }
  }
  float s1 = 0.f, s2 = 0.f;
  #pragma unroll
  for (int j = 0; j < 10; ++j) { s1 += b1[j]; s2 += b2[j]; }
  float pv = (s1 + s2) * 0.1f;
  pout[l] = pv;
  throut[l] = 2.f * diag[l] - pv;
}

// Combine scan partial (stored cols) + per-coltile partials (recomputed cols).
__global__ __launch_bounds__(256) void final_kernel(const int* __restrict__ cnt,
                                                    const float* __restrict__ mx,
                                                    const int* __restrict__ cnt_s,
                                                    const float* __restrict__ mx_s,
                                                    int sc,
                                                    float* __restrict__ out) {
  int r = blockIdx.x * 256 + threadIdx.x;
  int c = 0;
  float m = NEG_INF;
  if (sc > 0) { c = cnt_s[r]; m = mx_s[r]; }
  for (int s = sc; s < NCT; ++s) {
    c += cnt[(size_t)r * NCT + s];
    m = fmaxf(m, mx[(size_t)r * NCT + s]);
  }
  out[r] = (float)c;   // rank of the diagonal element (count strictly greater)
  out[NN + r] = m;     // top-1 csls value
}

extern "C" void kernel_launch(void* const* d_in, const int* in_sizes, int n_in,
                              void* d_out, int out_size, void* d_ws, size_t ws_size,
                              hipStream_t stream) {
  const float* L = (const float*)d_in[0];
  const float* R = (const float*)d_in[1];
  char* ws = (char*)d_ws;

  const size_t PARTB = (size_t)NN * NCT * KT * 2;       // 24 MiB per partial
  const size_t TAILOFF = (32ull << 20) + 2 * PARTB;     // 80 MiB
  const size_t SIMOFF = TAILOFF + (320ull << 10);       // 80.3125 MiB

  u16* Lb   = (u16*)ws;                                 // 16 MiB
  u16* Rb   = (u16*)(ws + (16ull << 20));               // 16 MiB
  f16* rowp = (f16*)(ws + (32ull << 20));               // 24 MiB [seg][row][KT]
  f16* colp = (f16*)(ws + (32ull << 20) + PARTB);       // 24 MiB [seg][col][KT]
  char* tail = ws + TAILOFF;
  float* diag   = (float*)tail;
  float* pbuf   = (float*)(tail + (64ull << 10));
  float* thrbuf = (float*)(tail + (128ull << 10));
  int*   cnt_s  = (int*)(tail + (192ull << 10));
  float* mx_s   = (float*)(tail + (256ull << 10));
  f16*   sim    = (f16*)(ws + SIMOFF);
  // cnt/mx alias partial regions (fully consumed by p_kernel first)
  int*   cntp = (int*)rowp;                             // 8.4 MB
  float* mxp  = (float*)colp;                           // 8.4 MB

  // Stored column-tiles: as many as the workspace holds (4 MiB each).
  int SC = 0;
  if (ws_size > SIMOFF) {
    size_t sc = (ws_size - SIMOFF) / ((size_t)NN * BN * 2);
    if (sc > 128) sc = 128;
    SC = (int)sc;
  }

  // 1) fp32 -> bf16 casts
  cast_kernel<<<(NN * DD / (256 * 8)), 256, 0, stream>>>(L, Lb);
  cast_kernel<<<(NN * DD / (256 * 8)), 256, 0, stream>>>(R, Rb);
  // 2) diagonal sim values
  diag_kernel<<<NN / 4, 256, 0, stream>>>(Lb, Rb, diag);
  // 3) pass 1 over G2 = R*L^T: top-6 partials + sim store for coltile < SC
  gemm_topk<<<(NN / BM) * (NN / BN), 256, 0, stream>>>(Rb, Lb, rowp, colp, sim, SC);
  // 4) merge partials -> p, thr
  p_kernel<<<NN / 256, 256, 0, stream>>>(rowp, colp, diag, pbuf, thrbuf);
  // 5a) stored columns: streaming scan
  if (SC > 0)
    scan_kernel<<<NN / 4, 256, 0, stream>>>(sim, pbuf, thrbuf, SC, cnt_s, mx_s);
  // 5b) remaining columns: recompute GEMM + rank
  if (SC < 128)
    gemm_rank<<<(NN / BM) * (128 - SC), 256, 0, stream>>>(Rb, Lb, pbuf, thrbuf,
                                                          cntp, mxp, SC);
  // 6) combine -> outputs
  final_kernel<<<NN / 256, 256, 0, stream>>>(cntp, mxp, cnt_s, mx_s, SC,
                                             (float*)d_out);
}

// Round 5
// 762.721 us; speedup vs baseline: 2.2334x; 1.1216x over previous
//
#include <hip/hip_runtime.h>
#include <hip/hip_bf16.h>
#include <stdint.h>

// Problem constants (fixed by setup_inputs)
#define NN 16384
#define DD 512
#define BM 128
#define BN 256        // R13: block tile 128x256, 4 waves of 64x128
#define NCT2 64       // 256-wide column tiles (= NN/BN)
#define KT 6          // per-tile top-k kept (global top-10 from 64x top-6)
#define EPW 264       // epilogue fp16 view pitch (128 rows x 264)
#define NEG_INF (-3.0e38f)

// R13: K-loop was LDS-throughput-bound (512 LDS-cyc vs 310 MFMA-cyc per
// 128x128 K-step; MfmaUtil 35%). Widen per-wave tile to 64x128: 12
// ds_read_b128 -> 32 MFMA (ratio 2.0->2.67) and A-panel staging shared
// over 2x output: LDS cycles/output -25%. acc 128 regs -> 2 blocks/CU
// (__launch_bounds__(256,2)); same counted-vmcnt dbuf skeleton (verified
// R12), now 12 loads in flight, wait vmcnt(6). Partials 48->37.7 MiB ->
// SC 43->46 stored col-units; gemm_rank covers 41 256-wide tiles.

typedef unsigned short u16;
typedef _Float16 f16;
typedef __attribute__((ext_vector_type(8))) __bf16 bf16x8;   // MFMA A/B operand
typedef __attribute__((ext_vector_type(8))) short sh8;       // 16B vector
typedef __attribute__((ext_vector_type(8))) _Float16 f16x8;  // 16B of fp16
typedef __attribute__((ext_vector_type(4))) float f32x4;     // MFMA C/D

__device__ __forceinline__ u16 f2bf(float f) {  // RNE fp32->bf16
  uint32_t x = __float_as_uint(f);
  x += 0x7fffu + ((x >> 16) & 1u);
  return (u16)(x >> 16);
}
__device__ __forceinline__ float bf2f(u16 u) {
  return __uint_as_float(((uint32_t)u) << 16);
}
__device__ __forceinline__ float f16bits(uint32_t bits) {  // low 16b as f16
  f16 h;
  u16 b = (u16)bits;
  __builtin_memcpy(&h, &b, 2);
  return (float)h;
}
__device__ __forceinline__ u16 h2bits(f16 h) {
  u16 b;
  __builtin_memcpy(&b, &h, 2);
  return b;
}
__device__ __forceinline__ uint32_t pk_max16(uint32_t a, uint32_t b) {
  uint32_t d;
  asm("v_pk_max_f16 %0, %1, %2" : "=v"(d) : "v"(a), "v"(b));
  return d;
}
__device__ __forceinline__ uint32_t pk_min16(uint32_t a, uint32_t b) {
  uint32_t d;
  asm("v_pk_min_f16 %0, %1, %2" : "=v"(d) : "v"(a), "v"(b));
  return d;
}

// async global->LDS, 16B per lane; lds base wave-uniform.
__device__ __forceinline__ void gload_lds16(const u16* g, u16* lds) {
  __builtin_amdgcn_global_load_lds(
      (const __attribute__((address_space(1))) uint32_t*)g,
      (__attribute__((address_space(3))) uint32_t*)lds,
      16, 0, 0);
}

// Insert v into descending-sorted N-element register array (fp32).
template <int N>
__device__ __forceinline__ void insN(float (&t)[N], float v) {
  #pragma unroll
  for (int j = 0; j < N; ++j) {
    float hi = fmaxf(t[j], v);
    v = fminf(t[j], v);
    t[j] = hi;
  }
}
// Packed variant: two independent sorted-desc f16 lists in lo/hi halves.
template <int N>
__device__ __forceinline__ void pinsN(uint32_t (&t)[N], uint32_t v) {
  #pragma unroll
  for (int j = 0; j < N; ++j) {
    uint32_t hi = pk_max16(t[j], v);
    v = pk_min16(t[j], v);
    t[j] = hi;
  }
}

__global__ __launch_bounds__(256) void cast_kernel(const float* __restrict__ src,
                                                   u16* __restrict__ dst) {
  int i = (blockIdx.x * 256 + threadIdx.x) * 8;
  const float4* s4 = reinterpret_cast<const float4*>(src + i);
  float4 a = s4[0], b = s4[1];
  sh8 o;
  o[0] = (short)f2bf(a.x); o[1] = (short)f2bf(a.y);
  o[2] = (short)f2bf(a.z); o[3] = (short)f2bf(a.w);
  o[4] = (short)f2bf(b.x); o[5] = (short)f2bf(b.y);
  o[6] = (short)f2bf(b.z); o[7] = (short)f2bf(b.w);
  *reinterpret_cast<sh8*>(dst + i) = o;
}

// diag[r] = <Lb_r, Rb_r> — one wave per row
__global__ __launch_bounds__(256) void diag_kernel(const u16* __restrict__ Lb,
                                                   const u16* __restrict__ Rb,
                                                   float* __restrict__ diag) {
  int r = blockIdx.x * 4 + (threadIdx.x >> 6);
  int lane = threadIdx.x & 63;
  sh8 a = *reinterpret_cast<const sh8*>(Lb + (size_t)r * DD + lane * 8);
  sh8 b = *reinterpret_cast<const sh8*>(Rb + (size_t)r * DD + lane * 8);
  float s = 0.f;
  #pragma unroll
  for (int j = 0; j < 8; ++j) s += bf2f((u16)a[j]) * bf2f((u16)b[j]);
  #pragma unroll
  for (int off = 32; off > 0; off >>= 1) s += __shfl_down(s, off);
  if (lane == 0) diag[r] = s;
}

// Block-coordinate decode: 128 rowtiles (BM=128) x 64 coltiles (BN=256).
// xcd = blk&7 -> fixed 16-rowtile A-band per XCD; coltile sweeps slowly.
#define DECODE_TILE(ct0)                                \
  const int xcd = blockIdx.x & 7;                       \
  const int idx = blockIdx.x >> 3;                      \
  const int rowtile = xcd * 16 + (idx & 15);            \
  const int coltile = (ct0) + (idx >> 4);               \
  const int rowbase = rowtile * BM;                     \
  const int colbase = coltile * BN;                     \
  const int tid = threadIdx.x;                          \
  const int w = tid >> 6;                               \
  const int lane = tid & 63;                            \
  const int quad = lane >> 4;                           \
  const int l16 = lane & 15;                            \
  const int wr = (w >> 1) * 64;                         \
  const int wc = (w & 1) * 128;                         \
  (void)xcd; (void)lane;

// ---- BK=32 double-buffered prefetch K-loop, wave tile 64x128 ----
// LDS per K-step: A 128x32 bf16 (8 KB, 512 granules) + B 256x32 (16 KB,
// 1024 granules). Super-row rp (=2 rows) of 8 granules, XOR-swizzled:
// linear slot (rp,g) holds global granule gp = g ^ (rp&7), gp>>2 = row
// parity, gp&3 = col-granule. Fragment read for (row,quad): slot
// g = (((row&1)<<2)|quad) ^ ((row>>1)&7) -> conflict-free b128 floor.
#define GEMM_PRE()                                                              \
  int garow_[2], gacol_[2], gbrow_[4], gbcol_[4];                               \
  _Pragma("unroll")                                                             \
  for (int i_ = 0; i_ < 2; ++i_) {                                              \
    int gl_ = tid + i_ * 256;                                                   \
    int rp_ = gl_ >> 3, gp_ = (gl_ & 7) ^ (rp_ & 7);                            \
    garow_[i_] = rp_ * 2 + (gp_ >> 2); gacol_[i_] = (gp_ & 3) * 8;              \
  }                                                                             \
  _Pragma("unroll")                                                             \
  for (int i_ = 0; i_ < 4; ++i_) {                                              \
    int gl_ = tid + i_ * 256;                                                   \
    int rp_ = gl_ >> 3, gp_ = (gl_ & 7) ^ (rp_ & 7);                            \
    gbrow_[i_] = rp_ * 2 + (gp_ >> 2); gbcol_[i_] = (gp_ & 3) * 8;              \
  }                                                                             \
  const u16* gA0_ = A + (size_t)(rowbase + garow_[0]) * DD + gacol_[0];         \
  const u16* gA1_ = A + (size_t)(rowbase + garow_[1]) * DD + gacol_[1];         \
  const u16* gB0_ = B + (size_t)(colbase + gbrow_[0]) * DD + gbcol_[0];         \
  const u16* gB1_ = B + (size_t)(colbase + gbrow_[1]) * DD + gbcol_[1];         \
  const u16* gB2_ = B + (size_t)(colbase + gbrow_[2]) * DD + gbcol_[2];         \
  const u16* gB3_ = B + (size_t)(colbase + gbrow_[3]) * DD + gbcol_[3];         \
  const int gsel_ = ((((l16) & 1) << 2) + quad) ^ (l16 >> 1);                   \
  const int rdA_ = (wr / 2 + (l16 >> 1)) * 64 + gsel_ * 8;                      \
  const int rdB_ = (wc / 2 + (l16 >> 1)) * 64 + gsel_ * 8;

#define STAGE(t, dA, dB)                                                        \
  gload_lds16(gA0_ + (t) * 32, (dA) + tid * 8);                                 \
  gload_lds16(gA1_ + (t) * 32, (dA) + 2048 + tid * 8);                          \
  gload_lds16(gB0_ + (t) * 32, (dB) + tid * 8);                                 \
  gload_lds16(gB1_ + (t) * 32, (dB) + 2048 + tid * 8);                          \
  gload_lds16(gB2_ + (t) * 32, (dB) + 4096 + tid * 8);                          \
  gload_lds16(gB3_ + (t) * 32, (dB) + 6144 + tid * 8);

#define GEMM_K_LOOP(sA0_, sA1_, sB0_, sB1_)                                     \
  f32x4 acc[4][8];                                                              \
  _Pragma("unroll")                                                             \
  for (int a_ = 0; a_ < 4; ++a_)                                                \
    _Pragma("unroll")                                                           \
    for (int b_ = 0; b_ < 8; ++b_) acc[a_][b_] = (f32x4){0.f, 0.f, 0.f, 0.f};   \
  {                                                                             \
    GEMM_PRE()                                                                  \
    u16* const bufA_[2] = {(sA0_), (sA1_)};                                     \
    u16* const bufB_[2] = {(sB0_), (sB1_)};                                     \
    STAGE(0, bufA_[0], bufB_[0])                                                \
    STAGE(1, bufA_[1], bufB_[1])                                                \
    _Pragma("unroll")                                                           \
    for (int t = 0; t < 16; ++t) {                                              \
      if (t < 15) { asm volatile("s_waitcnt vmcnt(6)" ::: "memory"); }          \
      else        { asm volatile("s_waitcnt vmcnt(0)" ::: "memory"); }          \
      __builtin_amdgcn_s_barrier();                                             \
      asm volatile("" ::: "memory");                                            \
      {                                                                         \
        const u16* cA_ = bufA_[t & 1];                                          \
        const u16* cB_ = bufB_[t & 1];                                          \
        bf16x8 af[4], bfv[8];                                                   \
        _Pragma("unroll")                                                       \
        for (int f = 0; f < 4; ++f)                                             \
          af[f]  = *reinterpret_cast<const bf16x8*>(cA_ + rdA_ + f * 512);      \
        _Pragma("unroll")                                                       \
        for (int f = 0; f < 8; ++f)                                             \
          bfv[f] = *reinterpret_cast<const bf16x8*>(cB_ + rdB_ + f * 512);      \
        _Pragma("unroll")                                                       \
        for (int fr = 0; fr < 4; ++fr)                                          \
          _Pragma("unroll")                                                     \
          for (int fc = 0; fc < 8; ++fc)                                        \
            acc[fr][fc] = __builtin_amdgcn_mfma_f32_16x16x32_bf16(af[fr], bfv[fc], acc[fr][fc], 0, 0, 0); \
      }                                                                         \
      asm volatile("" ::: "memory");                                            \
      __builtin_amdgcn_s_barrier();                                             \
      if (t + 2 < 16) { STAGE(t + 2, bufA_[t & 1], bufB_[t & 1]) }              \
    }                                                                           \
  }

// Pass 1: G2 tile + row top-6 partials (RL) + col top-6 partials (LR).
// rowp[coltile][row][6] f16 (64 segs); colp[rowtile][col][6] f16 (128 segs).
// coltile < SC2 additionally dumps the fp16 tile to sim (row-major, width
// SC2*BN) so pass 2 over those columns is a streaming scan.
__global__ __launch_bounds__(256, 2) void gemm_topk(const u16* __restrict__ A,
                                                    const u16* __restrict__ B,
                                                    f16* __restrict__ rowp,
                                                    f16* __restrict__ colp,
                                                    f16* __restrict__ sim,
                                                    int SC2) {
  __shared__ __align__(16) u16 smem[33792];  // 67584 B (epi view 128x264 f16)
  u16* sA0 = smem;
  u16* sA1 = smem + 4096;
  u16* sB0 = smem + 8192;
  u16* sB1 = smem + 16384;
  DECODE_TILE(0)
  GEMM_K_LOOP(sA0, sA1, sB0, sB1)

  // fp16 dump [128][264]
  f16* hC = reinterpret_cast<f16*>(smem);
  #pragma unroll
  for (int fr = 0; fr < 4; ++fr)
    #pragma unroll
    for (int fc = 0; fc < 8; ++fc)
      #pragma unroll
      for (int reg = 0; reg < 4; ++reg)
        hC[(wr + 16 * fr + quad * 4 + reg) * EPW + wc + 16 * fc + l16] =
            (f16)acc[fr][fc][reg];
  __syncthreads();
  // global sim store (stored columns only): 16 iters x 256 thr x 8 f16
  if (coltile < SC2) {
    const int SW = SC2 * BN;
    f16* gs = sim + (size_t)rowbase * SW + (size_t)coltile * BN;
    #pragma unroll
    for (int itw = 0; itw < 16; ++itw) {
      int idx2 = itw * 2048 + tid * 8;
      int rr = idx2 >> 8, cc = idx2 & 255;
      f16x8 v = *reinterpret_cast<const f16x8*>(hC + rr * EPW + cc);
      *reinterpret_cast<f16x8*>(gs + (size_t)rr * SW + cc) = v;
    }
  }
  // ---- packed row scan: thread owns (row = tid>>1, col-half = tid&1, 128
  // cols); lo half = even cols, hi = odd cols.
  uint32_t trow[KT];
  #pragma unroll
  for (int j = 0; j < KT; ++j) trow[j] = 0xFBFFFBFFu;  // -65504 packed
  {
    const u16* q = reinterpret_cast<const u16*>(hC) + (tid >> 1) * EPW + (tid & 1) * 128;
    #pragma unroll
    for (int c8 = 0; c8 < 16; ++c8) {
      uint4 ch = *reinterpret_cast<const uint4*>(q + c8 * 8);
      pinsN<KT>(trow, ch.x);
      pinsN<KT>(trow, ch.y);
      pinsN<KT>(trow, ch.z);
      pinsN<KT>(trow, ch.w);
    }
  }
  // ---- packed col scan: thread owns col-pair cp = tid&127 (cols 2cp,2cp+1),
  // row-half rh = tid>>7 (64 rows). lo half = col 2cp, hi = col 2cp+1.
  uint32_t tcol[KT];
  #pragma unroll
  for (int j = 0; j < KT; ++j) tcol[j] = 0xFBFFFBFFu;
  const int cp = tid & 127, rh = tid >> 7;
  {
    const u16* base = reinterpret_cast<const u16*>(hC) + rh * 64 * EPW + 2 * cp;
    #pragma unroll 8
    for (int i = 0; i < 64; ++i) {
      uint32_t v = *reinterpret_cast<const uint32_t*>(base + i * EPW);
      pinsN<KT>(tcol, v);
    }
  }
  __syncthreads();
  // write both list sets (disjoint smem regions), one barrier, merge both
  uint32_t* sCl = reinterpret_cast<uint32_t*>(smem);              // [128cp][2rh][KT]
  uint32_t* sRl = reinterpret_cast<uint32_t*>(smem) + 128 * 2 * KT;  // [128row][2half][KT]
  #pragma unroll
  for (int j = 0; j < KT; ++j) sCl[(cp * 2 + rh) * KT + j] = tcol[j];
  #pragma unroll
  for (int j = 0; j < KT; ++j) sRl[tid * KT + j] = trow[j];
  __syncthreads();
  {
    // col merge (all 256 threads) -> colp[rowtile][colbase+tid][KT]
    float best[KT];
    #pragma unroll
    for (int j = 0; j < KT; ++j) best[j] = NEG_INF;
    const int cpp = tid >> 1, par = tid & 1;
    for (int rhi = 0; rhi < 2; ++rhi)
      for (int j = 0; j < KT; ++j) {
        uint32_t u = sCl[(cpp * 2 + rhi) * KT + j];
        float v = f16bits(par ? (u >> 16) : u);
        if (v > best[KT - 1]) insN<KT>(best, v);
        else break;  // list sorted desc
      }
    f16* o = colp + ((size_t)rowtile * NN + colbase + tid) * KT;
    uint32_t w0 = h2bits((f16)best[0]) | ((uint32_t)h2bits((f16)best[1]) << 16);
    uint32_t w1 = h2bits((f16)best[2]) | ((uint32_t)h2bits((f16)best[3]) << 16);
    uint32_t w2 = h2bits((f16)best[4]) | ((uint32_t)h2bits((f16)best[5]) << 16);
    uint32_t* o32 = reinterpret_cast<uint32_t*>(o);
    o32[0] = w0; o32[1] = w1; o32[2] = w2;
  }
  if (tid < 128) {
    // row merge -> rowp[coltile][rowbase+tid][KT]
    float best[KT];
    #pragma unroll
    for (int j = 0; j < KT; ++j) best[j] = NEG_INF;
    for (int h = 0; h < 2; ++h)
      for (int par = 0; par < 2; ++par)
        for (int j = 0; j < KT; ++j) {
          uint32_t u = sRl[(tid * 2 + h) * KT + j];
          float v = f16bits(par ? (u >> 16) : u);
          if (v > best[KT - 1]) insN<KT>(best, v);
          else break;
        }
    f16* o = rowp + ((size_t)coltile * NN + rowbase + tid) * KT;
    uint32_t w0 = h2bits((f16)best[0]) | ((uint32_t)h2bits((f16)best[1]) << 16);
    uint32_t w1 = h2bits((f16)best[2]) | ((uint32_t)h2bits((f16)best[3]) << 16);
    uint32_t w2 = h2bits((f16)best[4]) | ((uint32_t)h2bits((f16)best[5]) << 16);
    uint32_t* o32 = reinterpret_cast<uint32_t*>(o);
    o32[0] = w0; o32[1] = w1; o32[2] = w2;
  }
}

// Pass 2 (recompute part): tiles with coltile >= ct0.
__global__ __launch_bounds__(256, 2) void gemm_rank(const u16* __restrict__ A,
                                                    const u16* __restrict__ B,
                                                    const float* __restrict__ p,
                                                    const float* __restrict__ thr,
                                                    int* __restrict__ cnt_out,
                                                    float* __restrict__ mx_out,
                                                    int ct0) {
  __shared__ __align__(16) u16 smem[24576];  // 49152 B
  u16* sA0 = smem;
  u16* sA1 = smem + 4096;
  u16* sB0 = smem + 8192;
  u16* sB1 = smem + 16384;
  DECODE_TILE(ct0)

  GEMM_K_LOOP(sA0, sA1, sB0, sB1)

  // epilogue-only loads (kept out of the K-loop to save live VGPRs)
  float thrv[16];
  #pragma unroll
  for (int i = 0; i < 16; ++i)
    thrv[i] = thr[rowbase + wr + 16 * (i >> 2) + quad * 4 + (i & 3)];
  float pv[8];
  #pragma unroll
  for (int fc = 0; fc < 8; ++fc) pv[fc] = p[colbase + wc + 16 * fc + l16];

  int cnt[16];
  float mx[16];
  #pragma unroll
  for (int i = 0; i < 16; ++i) { cnt[i] = 0; mx[i] = NEG_INF; }
  #pragma unroll
  for (int fc = 0; fc < 8; ++fc)
    #pragma unroll
    for (int fr = 0; fr < 4; ++fr)
      #pragma unroll
      for (int reg = 0; reg < 4; ++reg) {
        float t2 = 2.f * acc[fr][fc][reg] - pv[fc];
        int idx2 = fr * 4 + reg;
        cnt[idx2] += (t2 > thrv[idx2]) ? 1 : 0;
        mx[idx2] = fmaxf(mx[idx2], t2);
      }

  // reduce across 16 col-lanes, then combine the two col-half waves per row
  float* sMx = reinterpret_cast<float*>(smem);        // [4][64]
  int*   sCn = reinterpret_cast<int*>(smem) + 256;    // [4][64]
  #pragma unroll
  for (int idx2 = 0; idx2 < 16; ++idx2) {
    int c = cnt[idx2];
    float m = mx[idx2];
    #pragma unroll
    for (int off = 1; off < 16; off <<= 1) {
      c += __shfl_xor(c, off);
      m = fmaxf(m, __shfl_xor(m, off));
    }
    if (l16 == 0) {
      int rloc = 16 * (idx2 >> 2) + quad * 4 + (idx2 & 3);
      sMx[w * 64 + rloc] = m;
      sCn[w * 64 + rloc] = c;
    }
  }
  __syncthreads();
  if (tid < 128) {
    int half = tid >> 6, rloc = tid & 63;
    int c = sCn[(half * 2) * 64 + rloc] + sCn[(half * 2 + 1) * 64 + rloc];
    float m = fmaxf(sMx[(half * 2) * 64 + rloc], sMx[(half * 2 + 1) * 64 + rloc]);
    cnt_out[(size_t)(rowbase + tid) * NCT2 + coltile] = c;
    mx_out[(size_t)(rowbase + tid) * NCT2 + coltile] = m;
  }
}

// Pass 2 (stored part): streaming scan of fp16 sim (width SW = SC2*BN).
// 4 rows per block; writes one partial count/max per row.
__global__ __launch_bounds__(256) void scan_kernel(const f16* __restrict__ sim,
                                                   const float* __restrict__ p,
                                                   const float* __restrict__ thr,
                                                   int SC2,
                                                   int* __restrict__ cnt_s,
                                                   float* __restrict__ mx_s) {
  const int tid = threadIdx.x;
  const int row0 = blockIdx.x * 4;
  const int SW = SC2 * BN;
  float t[4];
  #pragma unroll
  for (int r = 0; r < 4; ++r) t[r] = thr[row0 + r];
  int cnt[4] = {0, 0, 0, 0};
  float m[4] = {NEG_INF, NEG_INF, NEG_INF, NEG_INF};
  for (int c0 = tid * 8; c0 < SW; c0 += 2048) {
    float pv[8];
    {
      const float4* p4 = reinterpret_cast<const float4*>(p + c0);
      float4 a = p4[0], b = p4[1];
      pv[0] = a.x; pv[1] = a.y; pv[2] = a.z; pv[3] = a.w;
      pv[4] = b.x; pv[5] = b.y; pv[6] = b.z; pv[7] = b.w;
    }
    #pragma unroll
    for (int r = 0; r < 4; ++r) {
      f16x8 v8 = *reinterpret_cast<const f16x8*>(sim + (size_t)(row0 + r) * SW + c0);
      #pragma unroll
      for (int j = 0; j < 8; ++j) {
        float t2 = 2.f * (float)v8[j] - pv[j];
        cnt[r] += (t2 > t[r]) ? 1 : 0;
        m[r] = fmaxf(m[r], t2);
      }
    }
  }
  __shared__ float sM[4][4];
  __shared__ int sC[4][4];
  const int lane = tid & 63, w = tid >> 6;
  #pragma unroll
  for (int r = 0; r < 4; ++r) {
    int c = cnt[r];
    float mm = m[r];
    #pragma unroll
    for (int off = 32; off > 0; off >>= 1) {
      c += __shfl_down(c, off);
      mm = fmaxf(mm, __shfl_down(mm, off));
    }
    if (lane == 0) { sC[r][w] = c; sM[r][w] = mm; }
  }
  __syncthreads();
  if (tid < 4) {
    int c = sC[tid][0] + sC[tid][1] + sC[tid][2] + sC[tid][3];
    float mm = fmaxf(fmaxf(sM[tid][0], sM[tid][1]), fmaxf(sM[tid][2], sM[tid][3]));
    cnt_s[row0 + tid] = c;
    mx_s[row0 + tid] = mm;
  }
}

// p[l] = mean(top10 of rowp[*][l]) + mean(top10 of colp[*][l]); thr = 2*diag - p
// rowp has 64 segments (256-wide tiles), colp 128 (128-row tiles).
__global__ __launch_bounds__(256) void p_kernel(const f16* __restrict__ rowp,
                                                const f16* __restrict__ colp,
                                                const float* __restrict__ diag,
                                                float* __restrict__ pout,
                                                float* __restrict__ throut) {
  int l = blockIdx.x * 256 + threadIdx.x;
  float b1[10], b2[10];
  #pragma unroll
  for (int j = 0; j < 10; ++j) { b1[j] = NEG_INF; b2[j] = NEG_INF; }
  for (int s = 0; s < NCT2; ++s) {
    const uint32_t* q1 = reinterpret_cast<const uint32_t*>(rowp + ((size_t)s * NN + l) * KT);
    #pragma unroll
    for (int d = 0; d < 3; ++d) {
      uint32_t u = q1[d];
      float v0 = f16bits(u), v1 = f16bits(u >> 16);
      if (v0 > b1[9]) insN<10>(b1, v0); else break;
      if (v1 > b1[9]) insN<10>(b1, v1); else break;
    }
  }
  for (int s = 0; s < 128; ++s) {
    const uint32_t* q2 = reinterpret_cast<const uint32_t*>(colp + ((size_t)s * NN + l) * KT);
    #pragma unroll
    for (int d = 0; d < 3; ++d) {
      uint32_t u = q2[d];
      float v0 = f16bits(u), v1 = f16bits(u >> 16);
      if (v0 > b2[9]) insN<10>(b2, v0); else break;
      if (v1 > b2[9]) insN<10>(b2, v1); else break;
    }
  }
  float s1 = 0.f, s2 = 0.f;
  #pragma unroll
  for (int j = 0; j < 10; ++j) { s1 += b1[j]; s2 += b2[j]; }
  float pv = (s1 + s2) * 0.1f;
  pout[l] = pv;
  throut[l] = 2.f * diag[l] - pv;
}

// Combine scan partial (stored cols) + per-coltile partials (recomputed cols).
__global__ __launch_bounds__(256) void final_kernel(const int* __restrict__ cnt,
                                                    const float* __restrict__ mx,
                                                    const int* __restrict__ cnt_s,
                                                    const float* __restrict__ mx_s,
                                                    int sc2,
                                                    float* __restrict__ out) {
  int r = blockIdx.x * 256 + threadIdx.x;
  int c = 0;
  float m = NEG_INF;
  if (sc2 > 0) { c = cnt_s[r]; m = mx_s[r]; }
  for (int s = sc2; s < NCT2; ++s) {
    c += cnt[(size_t)r * NCT2 + s];
    m = fmaxf(m, mx[(size_t)r * NCT2 + s]);
  }
  out[r] = (float)c;   // rank of the diagonal element (count strictly greater)
  out[NN + r] = m;     // top-1 csls value
}

extern "C" void kernel_launch(void* const* d_in, const int* in_sizes, int n_in,
                              void* d_out, int out_size, void* d_ws, size_t ws_size,
                              hipStream_t stream) {
  const float* L = (const float*)d_in[0];
  const float* R = (const float*)d_in[1];
  char* ws = (char*)d_ws;

  const size_t PART_ROW = (size_t)NCT2 * NN * KT * 2;   // 12.58 MB
  const size_t PART_COL = (size_t)128 * NN * KT * 2;    // 25.17 MB
  const size_t TAILOFF = (32ull << 20) + PART_ROW + PART_COL;
  const size_t SIMOFF = TAILOFF + (320ull << 10);

  u16* Lb   = (u16*)ws;                                 // 16 MiB
  u16* Rb   = (u16*)(ws + (16ull << 20));               // 16 MiB
  f16* rowp = (f16*)(ws + (32ull << 20));               // [64 seg][NN][KT]
  f16* colp = (f16*)(ws + (32ull << 20) + PART_ROW);    // [128 seg][NN][KT]
  char* tail = ws + TAILOFF;
  float* diag   = (float*)tail;
  float* pbuf   = (float*)(tail + (64ull << 10));
  float* thrbuf = (float*)(tail + (128ull << 10));
  int*   cnt_s  = (int*)(tail + (192ull << 10));
  float* mx_s   = (float*)(tail + (256ull << 10));
  f16*   sim    = (f16*)(ws + SIMOFF);
  // cnt/mx alias partial regions (fully consumed by p_kernel first)
  int*   cntp = (int*)rowp;                             // 4.2 MB
  float* mxp  = (float*)colp;                           // 4.2 MB

  // Stored 256-wide column-tiles: as many as the workspace holds (8 MiB each).
  int SC2 = 0;
  if (ws_size > SIMOFF) {
    size_t sc = (ws_size - SIMOFF) / ((size_t)NN * BN * 2);
    if (sc > 64) sc = 64;
    SC2 = (int)sc;
  }

  // 1) fp32 -> bf16 casts
  cast_kernel<<<(NN * DD / (256 * 8)), 256, 0, stream>>>(L, Lb);
  cast_kernel<<<(NN * DD / (256 * 8)), 256, 0, stream>>>(R, Rb);
  // 2) diagonal sim values
  diag_kernel<<<NN / 4, 256, 0, stream>>>(Lb, Rb, diag);
  // 3) pass 1 over G2 = R*L^T: top-6 partials + sim store for coltile < SC2
  gemm_topk<<<(NN / BM) * NCT2, 256, 0, stream>>>(Rb, Lb, rowp, colp, sim, SC2);
  // 4) merge partials -> p, thr
  p_kernel<<<NN / 256, 256, 0, stream>>>(rowp, colp, diag, pbuf, thrbuf);
  // 5a) stored columns: streaming scan
  if (SC2 > 0)
    scan_kernel<<<NN / 4, 256, 0, stream>>>(sim, pbuf, thrbuf, SC2, cnt_s, mx_s);
  // 5b) remaining columns: recompute GEMM + rank
  if (SC2 < NCT2)
    gemm_rank<<<(NN / BM) * (NCT2 - SC2), 256, 0, stream>>>(Rb, Lb, pbuf, thrbuf,
                                                            cntp, mxp, SC2);
  // 6) combine -> outputs
  final_kernel<<<NN / 256, 256, 0, stream>>>(cntp, mxp, cnt_s, mx_s, SC2,
                                             (float*)d_out);
}